// Round 1
// baseline (2013.164 us; speedup 1.0000x reference)
//
#include <hip/hip_runtime.h>
#include <hip/hip_bf16.h>

// GAT layer: N=50000 nodes, E=1.6M edges, DIN_N=128, DIN_E=64, DOUT_N=DOUT_E=64.
// Decomposition:
//   z = nfeats @ W_fc.T                       (K1)
//   p[n] = W_edge[:,0:64]@z[n] + b_edge       (K2)  (src part)
//   q[n] = W_edge[:,128:192]@z[n]             (K2)  (dst part)
//   feat[e] = lrelu(p[src] + W2@efeat[e] + q[dst])   (K3, bf16 MFMA)
//   a[e] = lrelu(lrelu(feat[e]·w_coef)); ex=exp(a); denom[dst]+=ex  (K3)
//   h[dst] += (ex/denom[dst]) * z[src]        (K4, atomics)
// Segment-max is skipped: a is O(+-4) so exp cannot overflow; alpha identical.

typedef __attribute__((ext_vector_type(8))) short short8;
typedef __attribute__((ext_vector_type(4))) float f32x4;

__device__ __forceinline__ short f2bf(float f) {
    union { float f; unsigned u; } v; v.f = f;
    unsigned r = v.u + 0x7fffu + ((v.u >> 16) & 1u);  // RNE
    return (short)(r >> 16);
}

__device__ __forceinline__ short8 pack8(float4 a, float4 b) {
    short8 r;
    r[0] = f2bf(a.x); r[1] = f2bf(a.y); r[2] = f2bf(a.z); r[3] = f2bf(a.w);
    r[4] = f2bf(b.x); r[5] = f2bf(b.y); r[6] = f2bf(b.z); r[7] = f2bf(b.w);
    return r;
}

// ---------------- K1: z = nfeats @ W_fc.T ----------------
// block 256 = 4 waves; block handles 16 nodes (4 per wave); W_fc^T in LDS.
__global__ __launch_bounds__(256) void k1_nodeproj(
    const float* __restrict__ nfeats, const float* __restrict__ W_fc,
    float* __restrict__ z)
{
    __shared__ float WT[128 * 64];   // WT[k][c] = W_fc[c][k], 32 KiB
    const int tid = threadIdx.x;
    for (int i = tid; i < 64 * 128; i += 256) {
        int c = i >> 7, k = i & 127;
        WT[k * 64 + c] = W_fc[i];
    }
    __syncthreads();
    const int wave = tid >> 6, lane = tid & 63;
    const int nb = blockIdx.x * 16 + wave * 4;
    for (int j = 0; j < 4; ++j) {
        const int n = nb + j;
        const float4* x4 = (const float4*)(nfeats + (long)n * 128);
        float acc = 0.f;
#pragma unroll
        for (int k4 = 0; k4 < 32; ++k4) {
            float4 x = x4[k4];
            acc += x.x * WT[(k4 * 4 + 0) * 64 + lane];
            acc += x.y * WT[(k4 * 4 + 1) * 64 + lane];
            acc += x.z * WT[(k4 * 4 + 2) * 64 + lane];
            acc += x.w * WT[(k4 * 4 + 3) * 64 + lane];
        }
        z[(long)n * 64 + lane] = acc;
    }
}

// ---------------- K2: p = W1@z + b, q = W3@z ----------------
__global__ __launch_bounds__(256) void k2_pq(
    const float* __restrict__ z, const float* __restrict__ W_edge,
    const float* __restrict__ b_edge,
    float* __restrict__ p, float* __restrict__ q)
{
    __shared__ float W1T[64 * 64];   // W1T[k][c] = W_edge[c][k]
    __shared__ float W3T[64 * 64];   // W3T[k][c] = W_edge[c][128+k]
    const int tid = threadIdx.x;
    for (int i = tid; i < 64 * 64; i += 256) {
        int c = i >> 6, k = i & 63;
        W1T[k * 64 + c] = W_edge[c * 192 + k];
        W3T[k * 64 + c] = W_edge[c * 192 + 128 + k];
    }
    __syncthreads();
    const int wave = tid >> 6, lane = tid & 63;
    const float bias = b_edge[lane];
    const int nb = blockIdx.x * 16 + wave * 4;
    for (int j = 0; j < 4; ++j) {
        const int n = nb + j;
        const float4* x4 = (const float4*)(z + (long)n * 64);
        float ap = bias, aq = 0.f;
#pragma unroll
        for (int k4 = 0; k4 < 16; ++k4) {
            float4 x = x4[k4];
            ap += x.x * W1T[(k4 * 4 + 0) * 64 + lane];
            aq += x.x * W3T[(k4 * 4 + 0) * 64 + lane];
            ap += x.y * W1T[(k4 * 4 + 1) * 64 + lane];
            aq += x.y * W3T[(k4 * 4 + 1) * 64 + lane];
            ap += x.z * W1T[(k4 * 4 + 2) * 64 + lane];
            aq += x.z * W3T[(k4 * 4 + 2) * 64 + lane];
            ap += x.w * W1T[(k4 * 4 + 3) * 64 + lane];
            aq += x.w * W3T[(k4 * 4 + 3) * 64 + lane];
        }
        p[(long)n * 64 + lane] = ap;
        q[(long)n * 64 + lane] = aq;
    }
}

// ---------------- K3: per-edge MFMA GEMM + logits + denom ----------------
// block 256 = 4 waves; each wave does 64 edges = 4 tiles of 16 edges.
// MFMA 16x16x32 bf16: A = efeat rows [16x64], B = W2^T [64x64] (in regs).
// C/D layout (m89-verified): col = lane&15, row = (lane>>4)*4 + reg.
__global__ __launch_bounds__(256) void k3_edges(
    const float* __restrict__ efeats, const int* __restrict__ src,
    const int* __restrict__ dst, const float* __restrict__ W_edge,
    const float* __restrict__ w_coef, const float* __restrict__ p,
    const float* __restrict__ q, float* __restrict__ feat_out,
    float* __restrict__ exbuf, float* __restrict__ denom)
{
    const int lane = threadIdx.x & 63;
    const int wave = threadIdx.x >> 6;
    const int l15 = lane & 15, g = lane >> 4;
    const long wbase = ((long)blockIdx.x * 4 + wave) * 64;

    // B fragments (W2 = W_edge[:,64:128]); same (g,b)->k map as A frags.
    short8 Bf[4][2];
    float wc[4];
#pragma unroll
    for (int t = 0; t < 4; ++t) {
        const int col = t * 16 + l15;
        wc[t] = w_coef[col];
#pragma unroll
        for (int kt = 0; kt < 2; ++kt) {
            const float* wp = W_edge + col * 192 + 64 + kt * 32 + g * 8;
            Bf[t][kt] = pack8(*(const float4*)wp, *(const float4*)(wp + 4));
        }
    }

    for (int tile = 0; tile < 4; ++tile) {
        const long eb = wbase + tile * 16;
        const float* ap = efeats + (eb + l15) * 64 + g * 8;
        short8 Af[2];
        Af[0] = pack8(*(const float4*)ap,        *(const float4*)(ap + 4));
        Af[1] = pack8(*(const float4*)(ap + 32), *(const float4*)(ap + 36));

        f32x4 acc[4];
#pragma unroll
        for (int t = 0; t < 4; ++t) acc[t] = (f32x4){0.f, 0.f, 0.f, 0.f};
#pragma unroll
        for (int t = 0; t < 4; ++t)
#pragma unroll
            for (int kt = 0; kt < 2; ++kt)
                acc[t] = __builtin_amdgcn_mfma_f32_16x16x32_bf16(
                    Af[kt], Bf[t][kt], acc[t], 0, 0, 0);

        int srcs[4], dsts[4];
#pragma unroll
        for (int r = 0; r < 4; ++r) {
            const long e = eb + g * 4 + r;
            srcs[r] = src[e];
            dsts[r] = dst[e];
        }

        float asum[4];
#pragma unroll
        for (int r = 0; r < 4; ++r) {
            const long e = eb + g * 4 + r;
            float s = 0.f;
#pragma unroll
            for (int t = 0; t < 4; ++t) {
                const int col = t * 16 + l15;
                float v = acc[t][r] + p[srcs[r] * 64 + col] + q[dsts[r] * 64 + col];
                v = (v >= 0.f) ? v : 0.01f * v;          // leaky_relu
                feat_out[e * 64 + col] = v;
                s += v * wc[t];
            }
            asum[r] = s;
        }
#pragma unroll
        for (int r = 0; r < 4; ++r) {
            float s = asum[r];
            s += __shfl_xor(s, 1, 16);
            s += __shfl_xor(s, 2, 16);
            s += __shfl_xor(s, 4, 16);
            s += __shfl_xor(s, 8, 16);
            s = (s >= 0.f) ? s : 0.01f * s;              // lrelu
            s = (s >= 0.f) ? s : 0.01f * s;              // lrelu again
            const float e_x = expf(s);                   // no max-sub needed, |s|<~8
            if (l15 == r) {
                exbuf[eb + g * 4 + r] = e_x;
                atomicAdd(&denom[dsts[r]], e_x);
            }
        }
    }
}

// ---------------- K4: h[dst] += alpha * z[src] ----------------
// block 256 = 4 waves; wave handles 16 edges (4 iters x 4 edges, 16 lanes/edge).
__global__ __launch_bounds__(256) void k4_aggregate(
    const int* __restrict__ src, const int* __restrict__ dst,
    const float* __restrict__ exbuf, const float* __restrict__ denom,
    const float* __restrict__ z, float* __restrict__ h)
{
    const int lane = threadIdx.x & 63;
    const int wave = threadIdx.x >> 6;
    const int l15 = lane & 15, g = lane >> 4;
    const long base = ((long)blockIdx.x * 4 + wave) * 16;
    for (int it = 0; it < 4; ++it) {
        const long e = base + it * 4 + g;
        const int s = src[e], d = dst[e];
        const float alpha = exbuf[e] / denom[d];
        const float4 zv = *(const float4*)(z + (long)s * 64 + l15 * 4);
        float* hp = h + (long)d * 64 + l15 * 4;
        atomicAdd(hp + 0, alpha * zv.x);
        atomicAdd(hp + 1, alpha * zv.y);
        atomicAdd(hp + 2, alpha * zv.z);
        atomicAdd(hp + 3, alpha * zv.w);
    }
}

extern "C" void kernel_launch(void* const* d_in, const int* in_sizes, int n_in,
                              void* d_out, int out_size, void* d_ws, size_t ws_size,
                              hipStream_t stream) {
    const float* nfeats = (const float*)d_in[0];
    const float* efeats = (const float*)d_in[1];
    const int*   src    = (const int*)d_in[2];
    const int*   dst    = (const int*)d_in[3];
    const float* W_fc   = (const float*)d_in[4];
    const float* W_edge = (const float*)d_in[5];
    const float* b_edge = (const float*)d_in[6];
    const float* w_coef = (const float*)d_in[7];

    const int  N = in_sizes[0] / 128;   // 50000
    const long E = in_sizes[2];         // 1600000

    float* h    = (float*)d_out;                 // [N,64]
    float* feat = (float*)d_out + (long)N * 64;  // [E,64]

    float* z     = (float*)d_ws;            // N*64
    float* p     = z + (long)N * 64;        // N*64
    float* q     = p + (long)N * 64;        // N*64
    float* exbuf = q + (long)N * 64;        // E
    float* denom = exbuf + E;               // N

    hipMemsetAsync(h, 0, (size_t)N * 64 * sizeof(float), stream);
    hipMemsetAsync(denom, 0, (size_t)N * sizeof(float), stream);

    k1_nodeproj<<<N / 16, 256, 0, stream>>>(nfeats, W_fc, z);
    k2_pq<<<N / 16, 256, 0, stream>>>(z, W_edge, b_edge, p, q);
    k3_edges<<<E / 256, 256, 0, stream>>>(efeats, src, dst, W_edge, w_coef,
                                          p, q, feat, exbuf, denom);
    k4_aggregate<<<E / 64, 256, 0, stream>>>(src, dst, exbuf, denom, z, h);
}

// Round 2
// 942.783 us; speedup vs baseline: 2.1353x; 2.1353x over previous
//
#include <hip/hip_runtime.h>
#include <hip/hip_bf16.h>

// GAT layer: N=50000 nodes, E=1.6M edges, DIN_N=128, DIN_E=64, DOUT_N=DOUT_E=64.
// Decomposition:
//   z = nfeats @ W_fc.T                       (K1)
//   p[n] = W_edge[:,0:64]@z[n] + b_edge       (K2)
//   q[n] = W_edge[:,128:192]@z[n]             (K2)
//   feat[e] = lrelu(p[src] + W2@efeat[e] + q[dst])   (K3, bf16 MFMA)
//   a[e] = lrelu(lrelu(feat[e]·w_coef)); ex=exp(a); deg[dst]++      (K3)
//   CSR build: off = exscan(deg) (K_scan); scatter sorted (src,ex) (K_scatter)
//   h[n] = sum_e ex*z[src] / sum_e ex   per node, register reduce   (K5)
// Segment-max skipped: a is O(+-4) so exp cannot overflow; alpha identical.
// R1->R2: killed k4's 102M float atomics (1357us, 1.8GB write traffic) via
// dst-CSR + per-node wave reduction.

typedef __attribute__((ext_vector_type(8))) short short8;
typedef __attribute__((ext_vector_type(4))) float f32x4;

__device__ __forceinline__ short f2bf(float f) {
    union { float f; unsigned u; } v; v.f = f;
    unsigned r = v.u + 0x7fffu + ((v.u >> 16) & 1u);  // RNE
    return (short)(r >> 16);
}

__device__ __forceinline__ short8 pack8(float4 a, float4 b) {
    short8 r;
    r[0] = f2bf(a.x); r[1] = f2bf(a.y); r[2] = f2bf(a.z); r[3] = f2bf(a.w);
    r[4] = f2bf(b.x); r[5] = f2bf(b.y); r[6] = f2bf(b.z); r[7] = f2bf(b.w);
    return r;
}

// ---------------- K1: z = nfeats @ W_fc.T ----------------
__global__ __launch_bounds__(256) void k1_nodeproj(
    const float* __restrict__ nfeats, const float* __restrict__ W_fc,
    float* __restrict__ z)
{
    __shared__ float WT[128 * 64];   // WT[k][c] = W_fc[c][k], 32 KiB
    const int tid = threadIdx.x;
    for (int i = tid; i < 64 * 128; i += 256) {
        int c = i >> 7, k = i & 127;
        WT[k * 64 + c] = W_fc[i];
    }
    __syncthreads();
    const int wave = tid >> 6, lane = tid & 63;
    const int nb = blockIdx.x * 16 + wave * 4;
    for (int j = 0; j < 4; ++j) {
        const int n = nb + j;
        const float4* x4 = (const float4*)(nfeats + (long)n * 128);
        float acc = 0.f;
#pragma unroll
        for (int k4 = 0; k4 < 32; ++k4) {
            float4 x = x4[k4];
            acc += x.x * WT[(k4 * 4 + 0) * 64 + lane];
            acc += x.y * WT[(k4 * 4 + 1) * 64 + lane];
            acc += x.z * WT[(k4 * 4 + 2) * 64 + lane];
            acc += x.w * WT[(k4 * 4 + 3) * 64 + lane];
        }
        z[(long)n * 64 + lane] = acc;
    }
}

// ---------------- K2: p = W1@z + b, q = W3@z ----------------
__global__ __launch_bounds__(256) void k2_pq(
    const float* __restrict__ z, const float* __restrict__ W_edge,
    const float* __restrict__ b_edge,
    float* __restrict__ p, float* __restrict__ q)
{
    __shared__ float W1T[64 * 64];
    __shared__ float W3T[64 * 64];
    const int tid = threadIdx.x;
    for (int i = tid; i < 64 * 64; i += 256) {
        int c = i >> 6, k = i & 63;
        W1T[k * 64 + c] = W_edge[c * 192 + k];
        W3T[k * 64 + c] = W_edge[c * 192 + 128 + k];
    }
    __syncthreads();
    const int wave = tid >> 6, lane = tid & 63;
    const float bias = b_edge[lane];
    const int nb = blockIdx.x * 16 + wave * 4;
    for (int j = 0; j < 4; ++j) {
        const int n = nb + j;
        const float4* x4 = (const float4*)(z + (long)n * 64);
        float ap = bias, aq = 0.f;
#pragma unroll
        for (int k4 = 0; k4 < 16; ++k4) {
            float4 x = x4[k4];
            ap += x.x * W1T[(k4 * 4 + 0) * 64 + lane];
            aq += x.x * W3T[(k4 * 4 + 0) * 64 + lane];
            ap += x.y * W1T[(k4 * 4 + 1) * 64 + lane];
            aq += x.y * W3T[(k4 * 4 + 1) * 64 + lane];
            ap += x.z * W1T[(k4 * 4 + 2) * 64 + lane];
            aq += x.z * W3T[(k4 * 4 + 2) * 64 + lane];
            ap += x.w * W1T[(k4 * 4 + 3) * 64 + lane];
            aq += x.w * W3T[(k4 * 4 + 3) * 64 + lane];
        }
        p[(long)n * 64 + lane] = ap;
        q[(long)n * 64 + lane] = aq;
    }
}

// ---------------- K3: per-edge MFMA GEMM + logits + deg count ----------------
// C/D layout (m89-verified): col = lane&15, row = (lane>>4)*4 + reg.
__global__ __launch_bounds__(256) void k3_edges(
    const float* __restrict__ efeats, const int* __restrict__ src,
    const int* __restrict__ dst, const float* __restrict__ W_edge,
    const float* __restrict__ w_coef, const float* __restrict__ p,
    const float* __restrict__ q, float* __restrict__ feat_out,
    float* __restrict__ exbuf, int* __restrict__ deg)
{
    const int lane = threadIdx.x & 63;
    const int wave = threadIdx.x >> 6;
    const int l15 = lane & 15, g = lane >> 4;
    const long wbase = ((long)blockIdx.x * 4 + wave) * 64;

    // B fragments (W2 = W_edge[:,64:128]); same (g,b)->k map as A frags.
    short8 Bf[4][2];
    float wc[4];
#pragma unroll
    for (int t = 0; t < 4; ++t) {
        const int col = t * 16 + l15;
        wc[t] = w_coef[col];
#pragma unroll
        for (int kt = 0; kt < 2; ++kt) {
            const float* wp = W_edge + col * 192 + 64 + kt * 32 + g * 8;
            Bf[t][kt] = pack8(*(const float4*)wp, *(const float4*)(wp + 4));
        }
    }

    for (int tile = 0; tile < 4; ++tile) {
        const long eb = wbase + tile * 16;
        const float* ap = efeats + (eb + l15) * 64 + g * 8;
        short8 Af[2];
        Af[0] = pack8(*(const float4*)ap,        *(const float4*)(ap + 4));
        Af[1] = pack8(*(const float4*)(ap + 32), *(const float4*)(ap + 36));

        f32x4 acc[4];
#pragma unroll
        for (int t = 0; t < 4; ++t) acc[t] = (f32x4){0.f, 0.f, 0.f, 0.f};
#pragma unroll
        for (int t = 0; t < 4; ++t)
#pragma unroll
            for (int kt = 0; kt < 2; ++kt)
                acc[t] = __builtin_amdgcn_mfma_f32_16x16x32_bf16(
                    Af[kt], Bf[t][kt], acc[t], 0, 0, 0);

        int srcs[4], dsts[4];
#pragma unroll
        for (int r = 0; r < 4; ++r) {
            const long e = eb + g * 4 + r;
            srcs[r] = src[e];
            dsts[r] = dst[e];
        }

        float asum[4];
#pragma unroll
        for (int r = 0; r < 4; ++r) {
            const long e = eb + g * 4 + r;
            float s = 0.f;
#pragma unroll
            for (int t = 0; t < 4; ++t) {
                const int col = t * 16 + l15;
                float v = acc[t][r] + p[srcs[r] * 64 + col] + q[dsts[r] * 64 + col];
                v = (v >= 0.f) ? v : 0.01f * v;          // leaky_relu
                feat_out[e * 64 + col] = v;
                s += v * wc[t];
            }
            asum[r] = s;
        }
#pragma unroll
        for (int r = 0; r < 4; ++r) {
            float s = asum[r];
            s += __shfl_xor(s, 1, 16);
            s += __shfl_xor(s, 2, 16);
            s += __shfl_xor(s, 4, 16);
            s += __shfl_xor(s, 8, 16);
            s = (s >= 0.f) ? s : 0.01f * s;              // lrelu
            s = (s >= 0.f) ? s : 0.01f * s;              // lrelu again
            const float e_x = expf(s);                   // |s| small, no overflow
            if (l15 == r) {
                exbuf[eb + g * 4 + r] = e_x;
                atomicAdd(&deg[dsts[r]], 1);
            }
        }
    }
}

// ---------------- K_scan: off = exclusive_scan(deg), single block ----------------
__global__ __launch_bounds__(1024) void k_scan(
    const int* __restrict__ deg, int* __restrict__ off, int N)
{
    __shared__ int wsum[16];
    const int tid = threadIdx.x;
    const int lane = tid & 63, wave = tid >> 6;
    int carry = 0;
    for (int base = 0; base < N; base += 1024) {
        const int i = base + tid;
        const int v = (i < N) ? deg[i] : 0;
        int x = v;
#pragma unroll
        for (int d = 1; d < 64; d <<= 1) {
            int y = __shfl_up(x, d, 64);
            if (lane >= d) x += y;
        }
        if (lane == 63) wsum[wave] = x;
        __syncthreads();
        int wprefix = 0, total = 0;
#pragma unroll
        for (int w = 0; w < 16; ++w) {
            const int s = wsum[w];
            if (w < wave) wprefix += s;
            total += s;
        }
        if (i < N) off[i] = carry + wprefix + (x - v);
        carry += total;
        __syncthreads();
    }
    if (tid == 0) off[N] = carry;
}

// ---------------- K_scatter: sorted (src, ex) by dst ----------------
__global__ __launch_bounds__(256) void k_scatter(
    const int* __restrict__ src, const int* __restrict__ dst,
    const float* __restrict__ exbuf, const int* __restrict__ off,
    int* __restrict__ cursor, int* __restrict__ ssrc, float* __restrict__ sex,
    long E)
{
    const long e = (long)blockIdx.x * 256 + threadIdx.x;
    if (e >= E) return;
    const int d = dst[e];
    const int pos = off[d] + atomicAdd(&cursor[d], 1);
    ssrc[pos] = src[e];
    sex[pos]  = exbuf[e];
}

// ---------------- K5: per-node softmax-normalize + aggregate ----------------
// one wave per node; lane = output channel.
__global__ __launch_bounds__(256) void k5_aggregate(
    const int* __restrict__ off, const int* __restrict__ ssrc,
    const float* __restrict__ sex, const float* __restrict__ z,
    float* __restrict__ h, int N)
{
    const int wave = threadIdx.x >> 6, lane = threadIdx.x & 63;
    const int n = blockIdx.x * 4 + wave;
    if (n >= N) return;
    const int beg = off[n], end = off[n + 1];
    float den = 0.f, acc = 0.f;
    for (int i = beg; i < end; ++i) {
        const int s = ssrc[i];
        const float ex = sex[i];
        den += ex;
        acc += ex * z[(long)s * 64 + lane];
    }
    h[(long)n * 64 + lane] = (end > beg) ? (acc / den) : 0.f;
}

extern "C" void kernel_launch(void* const* d_in, const int* in_sizes, int n_in,
                              void* d_out, int out_size, void* d_ws, size_t ws_size,
                              hipStream_t stream) {
    const float* nfeats = (const float*)d_in[0];
    const float* efeats = (const float*)d_in[1];
    const int*   src    = (const int*)d_in[2];
    const int*   dst    = (const int*)d_in[3];
    const float* W_fc   = (const float*)d_in[4];
    const float* W_edge = (const float*)d_in[5];
    const float* b_edge = (const float*)d_in[6];
    const float* w_coef = (const float*)d_in[7];

    const int  N = in_sizes[0] / 128;   // 50000
    const long E = in_sizes[2];         // 1600000

    float* h    = (float*)d_out;                 // [N,64]
    float* feat = (float*)d_out + (long)N * 64;  // [E,64]

    float* z      = (float*)d_ws;              // N*64
    float* p      = z + (long)N * 64;          // N*64
    float* q      = p + (long)N * 64;          // N*64
    float* exbuf  = q + (long)N * 64;          // E
    int*   deg    = (int*)(exbuf + E);         // N   (zeroed)
    int*   cursor = deg + N;                   // N   (zeroed)
    int*   off    = cursor + N;                // N+1
    int*   ssrc   = off + N + 2;               // E
    float* sex    = (float*)(ssrc + E);        // E

    hipMemsetAsync(deg, 0, (size_t)2 * N * sizeof(int), stream);  // deg + cursor

    k1_nodeproj<<<N / 16, 256, 0, stream>>>(nfeats, W_fc, z);
    k2_pq<<<N / 16, 256, 0, stream>>>(z, W_edge, b_edge, p, q);
    k3_edges<<<(int)(E / 256), 256, 0, stream>>>(efeats, src, dst, W_edge, w_coef,
                                                 p, q, feat, exbuf, deg);
    k_scan<<<1, 1024, 0, stream>>>(deg, off, N);
    k_scatter<<<(int)((E + 255) / 256), 256, 0, stream>>>(src, dst, exbuf, off,
                                                          cursor, ssrc, sex, E);
    k5_aggregate<<<(N + 3) / 4, 256, 0, stream>>>(off, ssrc, sex, z, h, N);
}

// Round 5
// 681.024 us; speedup vs baseline: 2.9561x; 1.3844x over previous
//
#include <hip/hip_runtime.h>
#include <hip/hip_bf16.h>

// GAT layer: N=50000 nodes, E=1.6M edges, DIN_N=128, DIN_E=64, DOUT_N=DOUT_E=64.
//   z = nfeats @ W_fc.T; p = W1@z + b; q = W3@z          (K12, fused)
//   feat[e] = lrelu([ef | p[src] | q[dst]] @ [W2; I; I])  (K3, K=192 MFMA,
//                         identity-B frags do the A->C transpose of p/q)
//   a = lrelu(lrelu(feat . wc)); ex = exp(a); deg[dst]++  (K3)
//   off = exscan(deg)  (scan1/2/3, multi-block)
//   pairs[off[d]+cur] = {src, ex}                         (scatter)
//   h[n] = sum(ex * z[src]) / sum(ex)                     (K5, wave/node)
// Segment-max skipped: a is O(+-4) so exp cannot overflow; alpha identical.
// R4->R5: resubmit (container died before compile).

typedef __attribute__((ext_vector_type(8))) short short8;
typedef __attribute__((ext_vector_type(4))) float f32x4;
typedef __attribute__((ext_vector_type(2))) int i32x2;

__device__ __forceinline__ short f2bf(float f) {
    union { float f; unsigned u; } v; v.f = f;
    unsigned r = v.u + 0x7fffu + ((v.u >> 16) & 1u);  // RNE
    return (short)(r >> 16);
}

__device__ __forceinline__ short8 pack8(f32x4 a, f32x4 b) {
    short8 r;
    r[0] = f2bf(a[0]); r[1] = f2bf(a[1]); r[2] = f2bf(a[2]); r[3] = f2bf(a[3]);
    r[4] = f2bf(b[0]); r[5] = f2bf(b[1]); r[6] = f2bf(b[2]); r[7] = f2bf(b[3]);
    return r;
}

__device__ __forceinline__ f32x4 ntld4(const float* p) {
    return __builtin_nontemporal_load((const f32x4*)p);
}

__device__ __forceinline__ f32x4 ld4(const float* p) {
    return *(const f32x4*)p;
}

// ---------------- K12: z = nfeats@W_fc.T; p = W1@z+b; q = W3@z ----------------
__global__ __launch_bounds__(256) void k12_node(
    const float* __restrict__ nfeats, const float* __restrict__ W_fc,
    const float* __restrict__ W_edge, const float* __restrict__ b_edge,
    float* __restrict__ z, float* __restrict__ p, float* __restrict__ q)
{
    __shared__ float WT[128 * 64];   // WT[k][c] = W_fc[c][k]
    __shared__ float W1T[64 * 64];   // W1T[k][c] = W_edge[c][k]
    __shared__ float W3T[64 * 64];   // W3T[k][c] = W_edge[c][128+k]
    __shared__ float zbuf[4][4][64];
    const int tid = threadIdx.x;
    for (int i = tid; i < 64 * 128; i += 256) {
        int c = i >> 7, k = i & 127;
        WT[k * 64 + c] = W_fc[i];
    }
    for (int i = tid; i < 64 * 64; i += 256) {
        int c = i >> 6, k = i & 63;
        W1T[k * 64 + c] = W_edge[c * 192 + k];
        W3T[k * 64 + c] = W_edge[c * 192 + 128 + k];
    }
    __syncthreads();
    const int wave = tid >> 6, lane = tid & 63;
    const float bias = b_edge[lane];
    const int nb = blockIdx.x * 16 + wave * 4;
    for (int j = 0; j < 4; ++j) {
        const int n = nb + j;
        const float* x = nfeats + (long)n * 128;
        float acc = 0.f;
#pragma unroll
        for (int k4 = 0; k4 < 32; ++k4) {
            f32x4 xv = ntld4(x + k4 * 4);
            acc += xv[0] * WT[(k4 * 4 + 0) * 64 + lane];
            acc += xv[1] * WT[(k4 * 4 + 1) * 64 + lane];
            acc += xv[2] * WT[(k4 * 4 + 2) * 64 + lane];
            acc += xv[3] * WT[(k4 * 4 + 3) * 64 + lane];
        }
        zbuf[wave][j][lane] = acc;
        z[(long)n * 64 + lane] = acc;
    }
    // same wave consumes its own zbuf rows; compiler inserts lgkmcnt
    for (int j = 0; j < 4; ++j) {
        const int n = nb + j;
        float ap = bias, aq = 0.f;
#pragma unroll
        for (int k = 0; k < 64; ++k) {
            const float zk = zbuf[wave][j][k];
            ap += zk * W1T[k * 64 + lane];
            aq += zk * W3T[k * 64 + lane];
        }
        p[(long)n * 64 + lane] = ap;
        q[(long)n * 64 + lane] = aq;
    }
}

// ---------------- K3: per-edge K=192 MFMA + logits + deg ----------------
// C/D layout (m89-verified): col = lane&15, row = (lane>>4)*4 + reg.
// A/B fragments filled with the same (g,j)->k bijection (validated R1/R2).
__global__ __launch_bounds__(256) void k3_edges(
    const float* __restrict__ efeats, const int* __restrict__ src,
    const int* __restrict__ dst, const float* __restrict__ W_edge,
    const float* __restrict__ w_coef, const float* __restrict__ p,
    const float* __restrict__ q, float* __restrict__ feat_out,
    float* __restrict__ exbuf, int* __restrict__ deg)
{
    const int lane = threadIdx.x & 63;
    const int wave = threadIdx.x >> 6;
    const int l15 = lane & 15, g = lane >> 4;
    const long wbase = ((long)blockIdx.x * 4 + wave) * 64;

    // W2 B-fragments: Bef[kt][t] elem j = W_edge[col][64 + kt*32 + g*8 + j]
    short8 Bef[2][4];
    float wc[4];
#pragma unroll
    for (int t = 0; t < 4; ++t) {
        const int col = t * 16 + l15;
        wc[t] = w_coef[col];
#pragma unroll
        for (int kt = 0; kt < 2; ++kt) {
            const float* wp = W_edge + col * 192 + 64 + kt * 32 + g * 8;
            Bef[kt][t] = pack8(ld4(wp), ld4(wp + 4));
        }
    }
    // identity B-fragments: one-hot at kc == col (mod 32 block)
    const short one = (short)0x3F80;   // bf16 1.0
    short8 IdA, IdB;
#pragma unroll
    for (int jj = 0; jj < 8; ++jj) {
        IdA[jj] = (l15 == g * 8 + jj) ? one : (short)0;        // cols 0..15 / 32..47
        IdB[jj] = (16 + l15 == g * 8 + jj) ? one : (short)0;   // cols 16..31 / 48..63
    }

    for (int tile = 0; tile < 4; ++tile) {
        const long eb = wbase + tile * 16;
        const int sE = src[eb + l15];
        const int dE = dst[eb + l15];

        const float* efp = efeats + (eb + l15) * 64 + g * 8;
        short8 Aef0 = pack8(ntld4(efp),      ntld4(efp + 4));
        short8 Aef1 = pack8(ntld4(efp + 32), ntld4(efp + 36));
        const float* pp = p + (long)sE * 64 + g * 8;
        short8 Ap0 = pack8(ld4(pp),      ld4(pp + 4));
        short8 Ap1 = pack8(ld4(pp + 32), ld4(pp + 36));
        const float* qp = q + (long)dE * 64 + g * 8;
        short8 Aq0 = pack8(ld4(qp),      ld4(qp + 4));
        short8 Aq1 = pack8(ld4(qp + 32), ld4(qp + 36));

        f32x4 acc[4];
#pragma unroll
        for (int t = 0; t < 4; ++t) acc[t] = (f32x4){0.f, 0.f, 0.f, 0.f};
#pragma unroll
        for (int t = 0; t < 4; ++t) {
            acc[t] = __builtin_amdgcn_mfma_f32_16x16x32_bf16(Aef0, Bef[0][t], acc[t], 0, 0, 0);
            acc[t] = __builtin_amdgcn_mfma_f32_16x16x32_bf16(Aef1, Bef[1][t], acc[t], 0, 0, 0);
        }
        // p part (k=64..127): Ap0 hits cols 0..31 (IdA->t0, IdB->t1), Ap1 cols 32..63
        acc[0] = __builtin_amdgcn_mfma_f32_16x16x32_bf16(Ap0, IdA, acc[0], 0, 0, 0);
        acc[1] = __builtin_amdgcn_mfma_f32_16x16x32_bf16(Ap0, IdB, acc[1], 0, 0, 0);
        acc[2] = __builtin_amdgcn_mfma_f32_16x16x32_bf16(Ap1, IdA, acc[2], 0, 0, 0);
        acc[3] = __builtin_amdgcn_mfma_f32_16x16x32_bf16(Ap1, IdB, acc[3], 0, 0, 0);
        // q part (k=128..191)
        acc[0] = __builtin_amdgcn_mfma_f32_16x16x32_bf16(Aq0, IdA, acc[0], 0, 0, 0);
        acc[1] = __builtin_amdgcn_mfma_f32_16x16x32_bf16(Aq0, IdB, acc[1], 0, 0, 0);
        acc[2] = __builtin_amdgcn_mfma_f32_16x16x32_bf16(Aq1, IdA, acc[2], 0, 0, 0);
        acc[3] = __builtin_amdgcn_mfma_f32_16x16x32_bf16(Aq1, IdB, acc[3], 0, 0, 0);

        float asum[4];
#pragma unroll
        for (int r = 0; r < 4; ++r) {
            const long e = eb + g * 4 + r;
            float s = 0.f;
#pragma unroll
            for (int t = 0; t < 4; ++t) {
                float v = acc[t][r];
                v = (v >= 0.f) ? v : 0.01f * v;          // leaky_relu
                __builtin_nontemporal_store(v, feat_out + e * 64 + t * 16 + l15);
                s += v * wc[t];
            }
            asum[r] = s;
        }
#pragma unroll
        for (int r = 0; r < 4; ++r) {
            float s = asum[r];
            s += __shfl_xor(s, 1, 16);
            s += __shfl_xor(s, 2, 16);
            s += __shfl_xor(s, 4, 16);
            s += __shfl_xor(s, 8, 16);
            s = (s >= 0.f) ? s : 0.01f * s;              // lrelu
            s = (s >= 0.f) ? s : 0.01f * s;              // lrelu again
            const float e_x = expf(s);                   // |s| small, no overflow
            const int dr = __shfl(dE, g * 4 + r, 16);    // dst[eb + g*4 + r]
            if (l15 == r) {
                exbuf[eb + g * 4 + r] = e_x;
                atomicAdd(&deg[dr], 1);
            }
        }
    }
}

// ---------------- scan1: per-block (1024 elems) totals ----------------
__global__ __launch_bounds__(256) void k_scan1(
    const int* __restrict__ deg, int* __restrict__ bsum, int N)
{
    __shared__ int ws4[4];
    const int tid = threadIdx.x, lane = tid & 63, wave = tid >> 6;
    const int i0 = blockIdx.x * 1024 + tid * 4;
    int s = 0;
#pragma unroll
    for (int jj = 0; jj < 4; ++jj) {
        const int i = i0 + jj;
        if (i < N) s += deg[i];
    }
#pragma unroll
    for (int d = 1; d < 64; d <<= 1) s += __shfl_xor(s, d, 64);
    if (lane == 0) ws4[wave] = s;
    __syncthreads();
    if (tid == 0) bsum[blockIdx.x] = ws4[0] + ws4[1] + ws4[2] + ws4[3];
}

// ---------------- scan2: scan of block totals (<=64 blocks) ----------------
__global__ __launch_bounds__(64) void k_scan2(
    const int* __restrict__ bsum, int* __restrict__ bpre,
    int* __restrict__ off, int nb, int N)
{
    const int t = threadIdx.x;
    const int v = (t < nb) ? bsum[t] : 0;
    int x = v;
#pragma unroll
    for (int d = 1; d < 64; d <<= 1) {
        int y = __shfl_up(x, d, 64);
        if (t >= d) x += y;
    }
    if (t < nb) bpre[t] = x - v;
    if (t == 63) off[N] = x;   // grand total == E
}

// ---------------- scan3: write off[i] ----------------
__global__ __launch_bounds__(256) void k_scan3(
    const int* __restrict__ deg, const int* __restrict__ bpre,
    int* __restrict__ off, int N)
{
    __shared__ int ws4[4];
    const int tid = threadIdx.x, lane = tid & 63, wave = tid >> 6;
    const int i0 = blockIdx.x * 1024 + tid * 4;
    int v[4];
#pragma unroll
    for (int jj = 0; jj < 4; ++jj) {
        const int i = i0 + jj;
        v[jj] = (i < N) ? deg[i] : 0;
    }
    const int s = v[0] + v[1] + v[2] + v[3];
    int x = s;
#pragma unroll
    for (int d = 1; d < 64; d <<= 1) {
        int y = __shfl_up(x, d, 64);
        if (lane >= d) x += y;
    }
    if (lane == 63) ws4[wave] = x;
    __syncthreads();
    int wpre = 0;
#pragma unroll
    for (int w = 0; w < 4; ++w) if (w < wave) wpre += ws4[w];
    int run = bpre[blockIdx.x] + wpre + (x - s);
#pragma unroll
    for (int jj = 0; jj < 4; ++jj) {
        const int i = i0 + jj;
        if (i < N) off[i] = run;
        run += v[jj];
    }
}

// ---------------- scatter: pairs[pos] = {src, ex} sorted by dst ----------------
__global__ __launch_bounds__(256) void k_scatter(
    const int* __restrict__ src, const int* __restrict__ dst,
    const float* __restrict__ exbuf, const int* __restrict__ off,
    int* __restrict__ cursor, i32x2* __restrict__ pairs, long E)
{
    const long e = (long)blockIdx.x * 256 + threadIdx.x;
    if (e >= E) return;
    const int d = dst[e];
    const int pos = off[d] + atomicAdd(&cursor[d], 1);
    i32x2 pr;
    pr[0] = src[e];
    pr[1] = __float_as_int(exbuf[e]);
    pairs[pos] = pr;
}

// ---------------- K5: h[n] = sum(ex*z[src]) / sum(ex) ----------------
__global__ __launch_bounds__(256) void k5_aggregate(
    const int* __restrict__ off, const i32x2* __restrict__ pairs,
    const float* __restrict__ z, float* __restrict__ h, int N)
{
    const int wave = threadIdx.x >> 6, lane = threadIdx.x & 63;
    const int n = blockIdx.x * 4 + wave;
    if (n >= N) return;
    const int beg = off[n], end = off[n + 1];
    float den = 0.f, acc = 0.f;
    for (int base = beg; base < end; base += 64) {
        const int rem = end - base;
        i32x2 pr = (i32x2){0, 0};
        if (lane < rem) pr = __builtin_nontemporal_load(&pairs[base + lane]);
        const float ex = __int_as_float(pr[1]);
        float t = ex;
#pragma unroll
        for (int d = 1; d < 64; d <<= 1) t += __shfl_xor(t, d, 64);
        den += t;
        const int cnt = rem < 64 ? rem : 64;
        for (int j = 0; j < cnt; ++j) {
            const int sN = __shfl(pr[0], j, 64);
            const float exj = __shfl(ex, j, 64);
            acc = fmaf(exj, z[(long)sN * 64 + lane], acc);
        }
    }
    __builtin_nontemporal_store((end > beg) ? acc / den : 0.f, h + (long)n * 64 + lane);
}

extern "C" void kernel_launch(void* const* d_in, const int* in_sizes, int n_in,
                              void* d_out, int out_size, void* d_ws, size_t ws_size,
                              hipStream_t stream) {
    const float* nfeats = (const float*)d_in[0];
    const float* efeats = (const float*)d_in[1];
    const int*   src    = (const int*)d_in[2];
    const int*   dst    = (const int*)d_in[3];
    const float* W_fc   = (const float*)d_in[4];
    const float* W_edge = (const float*)d_in[5];
    const float* b_edge = (const float*)d_in[6];
    const float* w_coef = (const float*)d_in[7];

    const int  N = in_sizes[0] / 128;   // 50000
    const long E = in_sizes[2];         // 1600000
    const int  nb = (N + 1023) / 1024;  // 49

    float* h    = (float*)d_out;                 // [N,64]
    float* feat = (float*)d_out + (long)N * 64;  // [E,64]

    float* z      = (float*)d_ws;              // N*64
    float* p      = z + (long)N * 64;          // N*64
    float* q      = p + (long)N * 64;          // N*64
    float* exbuf  = q + (long)N * 64;          // E
    int*   deg    = (int*)(exbuf + E);         // N
    int*   cursor = deg + N;                   // N
    int*   off    = cursor + N;                // N+2 (even pad, keeps pairs 8B-aligned)
    i32x2* pairs  = (i32x2*)(off + N + 2);     // E
    int*   bsum   = (int*)(pairs + E);         // 64
    int*   bpre   = bsum + 64;                 // 64

    (void)hipMemsetAsync(deg, 0, (size_t)2 * N * sizeof(int), stream);  // deg+cursor

    k12_node<<<N / 16, 256, 0, stream>>>(nfeats, W_fc, W_edge, b_edge, z, p, q);
    k3_edges<<<(int)(E / 256), 256, 0, stream>>>(efeats, src, dst, W_edge, w_coef,
                                                 p, q, feat, exbuf, deg);
    k_scan1<<<nb, 256, 0, stream>>>(deg, bsum, N);
    k_scan2<<<1, 64, 0, stream>>>(bsum, bpre, off, nb, N);
    k_scan3<<<nb, 256, 0, stream>>>(deg, bpre, off, N);
    k_scatter<<<(int)((E + 255) / 256), 256, 0, stream>>>(src, dst, exbuf, off,
                                                          cursor, pairs, E);
    k5_aggregate<<<(N + 3) / 4, 256, 0, stream>>>(off, pairs, z, h, N);
}

// Round 6
// 660.633 us; speedup vs baseline: 3.0473x; 1.0309x over previous
//
#include <hip/hip_runtime.h>
#include <hip/hip_bf16.h>

// GAT layer: N=50000 nodes, E=1.6M edges, DIN_N=128, DIN_E=64, DOUT_N=DOUT_E=64.
//   z = nfeats @ W_fc.T; p = W1@z + b; q = W3@z          (K12, fused)
//   feat[e] = lrelu([ef | p[src] | q[dst]] @ [W2; I; I])  (K3, K=192 MFMA,
//                         identity-B frags do the A->C transpose of p/q)
//   a = lrelu(lrelu(feat . wc)); ex = exp(a); deg[dst]++  (K3)
//   off = exscan(deg)  (scan1/2/3, multi-block)
//   pairs[off[d]+cur] = {src, ex}                         (scatter)
//   h[n] = sum(ex * z[src]) / sum(ex)                     (K5, wave/node)
// Segment-max skipped: a is O(+-4) so exp cannot overflow; alpha identical.
// R5->R6: k3 software-pipelined (p/q prefetch 1 tile ahead, shfl'd indices,
// cvt_pk packing, masked epilogue); k5 unrolled x4 with 4 accumulators.

typedef __attribute__((ext_vector_type(8))) short short8;
typedef __attribute__((ext_vector_type(4))) float f32x4;
typedef __attribute__((ext_vector_type(2))) int i32x2;

__device__ __forceinline__ short bf1(float f) {
    union { __hip_bfloat16 h; short s; } u;
    u.h = __float2bfloat16(f);          // compiler emits v_cvt_pk_bf16_f32 pairs
    return u.s;
}

__device__ __forceinline__ short8 pack8(f32x4 a, f32x4 b) {
    short8 r;
    r[0] = bf1(a[0]); r[1] = bf1(a[1]); r[2] = bf1(a[2]); r[3] = bf1(a[3]);
    r[4] = bf1(b[0]); r[5] = bf1(b[1]); r[6] = bf1(b[2]); r[7] = bf1(b[3]);
    return r;
}

__device__ __forceinline__ f32x4 ntld4(const float* p) {
    return __builtin_nontemporal_load((const f32x4*)p);
}

__device__ __forceinline__ f32x4 ld4(const float* p) {
    return *(const f32x4*)p;
}

#define MFMA16(A, B, C) __builtin_amdgcn_mfma_f32_16x16x32_bf16((A), (B), (C), 0, 0, 0)

// ---------------- K12: z = nfeats@W_fc.T; p = W1@z+b; q = W3@z ----------------
__global__ __launch_bounds__(256) void k12_node(
    const float* __restrict__ nfeats, const float* __restrict__ W_fc,
    const float* __restrict__ W_edge, const float* __restrict__ b_edge,
    float* __restrict__ z, float* __restrict__ p, float* __restrict__ q)
{
    __shared__ float WT[128 * 64];   // WT[k][c] = W_fc[c][k]
    __shared__ float W1T[64 * 64];   // W1T[k][c] = W_edge[c][k]
    __shared__ float W3T[64 * 64];   // W3T[k][c] = W_edge[c][128+k]
    __shared__ float zbuf[4][4][64];
    const int tid = threadIdx.x;
    for (int i = tid; i < 64 * 128; i += 256) {
        int c = i >> 7, k = i & 127;
        WT[k * 64 + c] = W_fc[i];
    }
    for (int i = tid; i < 64 * 64; i += 256) {
        int c = i >> 6, k = i & 63;
        W1T[k * 64 + c] = W_edge[c * 192 + k];
        W3T[k * 64 + c] = W_edge[c * 192 + 128 + k];
    }
    __syncthreads();
    const int wave = tid >> 6, lane = tid & 63;
    const float bias = b_edge[lane];
    const int nb = blockIdx.x * 16 + wave * 4;
    for (int j = 0; j < 4; ++j) {
        const int n = nb + j;
        const float* x = nfeats + (long)n * 128;
        float acc = 0.f;
#pragma unroll
        for (int k4 = 0; k4 < 32; ++k4) {
            f32x4 xv = ntld4(x + k4 * 4);
            acc += xv[0] * WT[(k4 * 4 + 0) * 64 + lane];
            acc += xv[1] * WT[(k4 * 4 + 1) * 64 + lane];
            acc += xv[2] * WT[(k4 * 4 + 2) * 64 + lane];
            acc += xv[3] * WT[(k4 * 4 + 3) * 64 + lane];
        }
        zbuf[wave][j][lane] = acc;
        z[(long)n * 64 + lane] = acc;
    }
    for (int j = 0; j < 4; ++j) {
        const int n = nb + j;
        float ap = bias, aq = 0.f;
#pragma unroll
        for (int k = 0; k < 64; ++k) {
            const float zk = zbuf[wave][j][k];
            ap += zk * W1T[k * 64 + lane];
            aq += zk * W3T[k * 64 + lane];
        }
        p[(long)n * 64 + lane] = ap;
        q[(long)n * 64 + lane] = aq;
    }
}

// ---------------- K3: per-edge K=192 MFMA + logits + deg (pipelined) ----------
// C/D layout (m89-verified): col = lane&15, row = (lane>>4)*4 + reg.
// A/B fragments filled with the same (g,j)->k bijection (validated R1/R2/R5).
#define LOAD_PQ(T, BUF) {                                                   \
    const int sE_ = __shfl(sAll, (T) * 16 + l15, 64);                       \
    const int dE_ = __shfl(dAll, (T) * 16 + l15, 64);                       \
    const float* pp_ = p + (long)sE_ * 64 + g * 8;                          \
    BUF[0] = ld4(pp_);      BUF[1] = ld4(pp_ + 4);                          \
    BUF[2] = ld4(pp_ + 32); BUF[3] = ld4(pp_ + 36);                         \
    const float* qp_ = q + (long)dE_ * 64 + g * 8;                          \
    BUF[4] = ld4(qp_);      BUF[5] = ld4(qp_ + 4);                          \
    BUF[6] = ld4(qp_ + 32); BUF[7] = ld4(qp_ + 36);                         \
}

#define DO_TILE(T, BUF, PREFETCH) {                                         \
    const long eb_ = wbase + (T) * 16;                                      \
    const float* efp_ = efeats + (eb_ + l15) * 64 + g * 8;                  \
    f32x4 ef0_ = ntld4(efp_),      ef1_ = ntld4(efp_ + 4);                  \
    f32x4 ef2_ = ntld4(efp_ + 32), ef3_ = ntld4(efp_ + 36);                 \
    PREFETCH                                                                \
    short8 Ap0_ = pack8(BUF[0], BUF[1]), Ap1_ = pack8(BUF[2], BUF[3]);      \
    short8 Aq0_ = pack8(BUF[4], BUF[5]), Aq1_ = pack8(BUF[6], BUF[7]);      \
    f32x4 acc_[4];                                                          \
    _Pragma("unroll")                                                       \
    for (int t = 0; t < 4; ++t) acc_[t] = (f32x4){0.f, 0.f, 0.f, 0.f};      \
    acc_[0] = MFMA16(Ap0_, IdA, acc_[0]);                                   \
    acc_[1] = MFMA16(Ap0_, IdB, acc_[1]);                                   \
    acc_[2] = MFMA16(Ap1_, IdA, acc_[2]);                                   \
    acc_[3] = MFMA16(Ap1_, IdB, acc_[3]);                                   \
    acc_[0] = MFMA16(Aq0_, IdA, acc_[0]);                                   \
    acc_[1] = MFMA16(Aq0_, IdB, acc_[1]);                                   \
    acc_[2] = MFMA16(Aq1_, IdA, acc_[2]);                                   \
    acc_[3] = MFMA16(Aq1_, IdB, acc_[3]);                                   \
    short8 Aef0_ = pack8(ef0_, ef1_), Aef1_ = pack8(ef2_, ef3_);            \
    _Pragma("unroll")                                                       \
    for (int t = 0; t < 4; ++t) {                                           \
        acc_[t] = MFMA16(Aef0_, Bef[0][t], acc_[t]);                        \
        acc_[t] = MFMA16(Aef1_, Bef[1][t], acc_[t]);                        \
    }                                                                       \
    float myex_ = 0.f;                                                      \
    _Pragma("unroll")                                                       \
    for (int r = 0; r < 4; ++r) {                                           \
        float s_ = 0.f;                                                     \
        _Pragma("unroll")                                                   \
        for (int t = 0; t < 4; ++t) {                                       \
            float v_ = acc_[t][r];                                          \
            v_ = (v_ >= 0.f) ? v_ : 0.01f * v_;                             \
            __builtin_nontemporal_store(v_,                                 \
                feat_out + (eb_ + g * 4 + r) * 64 + t * 16 + l15);          \
            s_ += v_ * wc[t];                                               \
        }                                                                   \
        s_ += __shfl_xor(s_, 1, 16);                                        \
        s_ += __shfl_xor(s_, 2, 16);                                        \
        s_ += __shfl_xor(s_, 4, 16);                                        \
        s_ += __shfl_xor(s_, 8, 16);                                        \
        s_ = (s_ >= 0.f) ? s_ : 0.01f * s_;                                 \
        s_ = (s_ >= 0.f) ? s_ : 0.01f * s_;                                 \
        const float ex_ = __expf(s_);                                       \
        if (l15 == r) myex_ = ex_;                                          \
    }                                                                       \
    const int dmine_ = __shfl(dAll, (T) * 16 + g * 4 + (l15 & 3), 64);      \
    if (l15 < 4) {                                                          \
        exbuf[eb_ + g * 4 + l15] = myex_;                                   \
        atomicAdd(&deg[dmine_], 1);                                         \
    }                                                                       \
}

__global__ __launch_bounds__(256, 2) void k3_edges(
    const float* __restrict__ efeats, const int* __restrict__ src,
    const int* __restrict__ dst, const float* __restrict__ W_edge,
    const float* __restrict__ w_coef, const float* __restrict__ p,
    const float* __restrict__ q, float* __restrict__ feat_out,
    float* __restrict__ exbuf, int* __restrict__ deg)
{
    const int lane = threadIdx.x & 63;
    const int wave = threadIdx.x >> 6;
    const int l15 = lane & 15, g = lane >> 4;
    const long wbase = ((long)blockIdx.x * 4 + wave) * 64;

    // W2 B-fragments: Bef[kt][t] elem j = W_edge[col][64 + kt*32 + g*8 + j]
    short8 Bef[2][4];
    float wc[4];
#pragma unroll
    for (int t = 0; t < 4; ++t) {
        const int col = t * 16 + l15;
        wc[t] = w_coef[col];
#pragma unroll
        for (int kt = 0; kt < 2; ++kt) {
            const float* wp = W_edge + col * 192 + 64 + kt * 32 + g * 8;
            Bef[kt][t] = pack8(ld4(wp), ld4(wp + 4));
        }
    }
    // identity B-fragments: one-hot at kc == col (mod 32 block)
    const short one = (short)0x3F80;   // bf16 1.0
    short8 IdA, IdB;
#pragma unroll
    for (int jj = 0; jj < 8; ++jj) {
        IdA[jj] = (l15 == g * 8 + jj) ? one : (short)0;        // cols 0..15 / 32..47
        IdB[jj] = (16 + l15 == g * 8 + jj) ? one : (short)0;   // cols 16..31 / 48..63
    }

    const int sAll = src[wbase + lane];
    const int dAll = dst[wbase + lane];

    f32x4 bufA[8], bufB[8];
    LOAD_PQ(0, bufA);
    DO_TILE(0, bufA, LOAD_PQ(1, bufB));
    DO_TILE(1, bufB, LOAD_PQ(2, bufA));
    DO_TILE(2, bufA, LOAD_PQ(3, bufB));
    DO_TILE(3, bufB, );
}

// ---------------- scan1: per-block (1024 elems) totals ----------------
__global__ __launch_bounds__(256) void k_scan1(
    const int* __restrict__ deg, int* __restrict__ bsum, int N)
{
    __shared__ int ws4[4];
    const int tid = threadIdx.x, lane = tid & 63, wave = tid >> 6;
    const int i0 = blockIdx.x * 1024 + tid * 4;
    int s = 0;
#pragma unroll
    for (int jj = 0; jj < 4; ++jj) {
        const int i = i0 + jj;
        if (i < N) s += deg[i];
    }
#pragma unroll
    for (int d = 1; d < 64; d <<= 1) s += __shfl_xor(s, d, 64);
    if (lane == 0) ws4[wave] = s;
    __syncthreads();
    if (tid == 0) bsum[blockIdx.x] = ws4[0] + ws4[1] + ws4[2] + ws4[3];
}

// ---------------- scan2: scan of block totals (<=64 blocks) ----------------
__global__ __launch_bounds__(64) void k_scan2(
    const int* __restrict__ bsum, int* __restrict__ bpre,
    int* __restrict__ off, int nb, int N)
{
    const int t = threadIdx.x;
    const int v = (t < nb) ? bsum[t] : 0;
    int x = v;
#pragma unroll
    for (int d = 1; d < 64; d <<= 1) {
        int y = __shfl_up(x, d, 64);
        if (t >= d) x += y;
    }
    if (t < nb) bpre[t] = x - v;
    if (t == 63) off[N] = x;   // grand total == E
}

// ---------------- scan3: write off[i] ----------------
__global__ __launch_bounds__(256) void k_scan3(
    const int* __restrict__ deg, const int* __restrict__ bpre,
    int* __restrict__ off, int N)
{
    __shared__ int ws4[4];
    const int tid = threadIdx.x, lane = tid & 63, wave = tid >> 6;
    const int i0 = blockIdx.x * 1024 + tid * 4;
    int v[4];
#pragma unroll
    for (int jj = 0; jj < 4; ++jj) {
        const int i = i0 + jj;
        v[jj] = (i < N) ? deg[i] : 0;
    }
    const int s = v[0] + v[1] + v[2] + v[3];
    int x = s;
#pragma unroll
    for (int d = 1; d < 64; d <<= 1) {
        int y = __shfl_up(x, d, 64);
        if (lane >= d) x += y;
    }
    if (lane == 63) ws4[wave] = x;
    __syncthreads();
    int wpre = 0;
#pragma unroll
    for (int w = 0; w < 4; ++w) if (w < wave) wpre += ws4[w];
    int run = bpre[blockIdx.x] + wpre + (x - s);
#pragma unroll
    for (int jj = 0; jj < 4; ++jj) {
        const int i = i0 + jj;
        if (i < N) off[i] = run;
        run += v[jj];
    }
}

// ---------------- scatter: pairs[pos] = {src, ex} sorted by dst ----------------
__global__ __launch_bounds__(256) void k_scatter(
    const int* __restrict__ src, const int* __restrict__ dst,
    const float* __restrict__ exbuf, const int* __restrict__ off,
    int* __restrict__ cursor, i32x2* __restrict__ pairs, long E)
{
    const long e = (long)blockIdx.x * 256 + threadIdx.x;
    if (e >= E) return;
    const int d = dst[e];
    const int pos = off[d] + atomicAdd(&cursor[d], 1);
    i32x2 pr;
    pr[0] = src[e];
    pr[1] = __float_as_int(exbuf[e]);
    pairs[pos] = pr;
}

// ---------------- K5: h[n] = sum(ex*z[src]) / sum(ex) ----------------
// one wave per node; lane = channel. Inner loop unrolled x4 with 4 accs;
// invalid lanes hold {0,0} so padded iterations add exactly 0.
__global__ __launch_bounds__(256) void k5_aggregate(
    const int* __restrict__ off, const i32x2* __restrict__ pairs,
    const float* __restrict__ z, float* __restrict__ h, int N)
{
    const int wave = threadIdx.x >> 6, lane = threadIdx.x & 63;
    const int n = blockIdx.x * 4 + wave;
    if (n >= N) return;
    const int beg = off[n], end = off[n + 1];
    float den = 0.f;
    float a0 = 0.f, a1 = 0.f, a2 = 0.f, a3 = 0.f;
    for (int base = beg; base < end; base += 64) {
        const int rem = end - base;
        i32x2 pr = (i32x2){0, 0};
        if (lane < rem) pr = __builtin_nontemporal_load(&pairs[base + lane]);
        const float ex = __int_as_float(pr[1]);
        float t = ex;
#pragma unroll
        for (int d = 1; d < 64; d <<= 1) t += __shfl_xor(t, d, 64);
        den += t;
        const int cnt = rem < 64 ? rem : 64;
        const int cnt4 = (cnt + 3) & ~3;
        for (int j = 0; j < cnt4; j += 4) {
            const int s0 = __shfl(pr[0], j, 64);
            const int s1 = __shfl(pr[0], j + 1, 64);
            const int s2 = __shfl(pr[0], j + 2, 64);
            const int s3 = __shfl(pr[0], j + 3, 64);
            const float e0 = __shfl(ex, j, 64);
            const float e1 = __shfl(ex, j + 1, 64);
            const float e2 = __shfl(ex, j + 2, 64);
            const float e3 = __shfl(ex, j + 3, 64);
            a0 = fmaf(e0, z[(long)s0 * 64 + lane], a0);
            a1 = fmaf(e1, z[(long)s1 * 64 + lane], a1);
            a2 = fmaf(e2, z[(long)s2 * 64 + lane], a2);
            a3 = fmaf(e3, z[(long)s3 * 64 + lane], a3);
        }
    }
    const float acc = (a0 + a1) + (a2 + a3);
    __builtin_nontemporal_store((end > beg) ? acc / den : 0.f,
                                h + (long)n * 64 + lane);
}

extern "C" void kernel_launch(void* const* d_in, const int* in_sizes, int n_in,
                              void* d_out, int out_size, void* d_ws, size_t ws_size,
                              hipStream_t stream) {
    const float* nfeats = (const float*)d_in[0];
    const float* efeats = (const float*)d_in[1];
    const int*   src    = (const int*)d_in[2];
    const int*   dst    = (const int*)d_in[3];
    const float* W_fc   = (const float*)d_in[4];
    const float* W_edge = (const float*)d_in[5];
    const float* b_edge = (const float*)d_in[6];
    const float* w_coef = (const float*)d_in[7];

    const int  N = in_sizes[0] / 128;   // 50000
    const long E = in_sizes[2];         // 1600000
    const int  nb = (N + 1023) / 1024;  // 49

    float* h    = (float*)d_out;                 // [N,64]
    float* feat = (float*)d_out + (long)N * 64;  // [E,64]

    float* z      = (float*)d_ws;              // N*64
    float* p      = z + (long)N * 64;          // N*64
    float* q      = p + (long)N * 64;          // N*64
    float* exbuf  = q + (long)N * 64;          // E
    int*   deg    = (int*)(exbuf + E);         // N
    int*   cursor = deg + N;                   // N
    int*   off    = cursor + N;                // N+2 (even pad, keeps pairs 8B-aligned)
    i32x2* pairs  = (i32x2*)(off + N + 2);     // E
    int*   bsum   = (int*)(pairs + E);         // 64
    int*   bpre   = bsum + 64;                 // 64

    (void)hipMemsetAsync(deg, 0, (size_t)2 * N * sizeof(int), stream);  // deg+cursor

    k12_node<<<N / 16, 256, 0, stream>>>(nfeats, W_fc, W_edge, b_edge, z, p, q);
    k3_edges<<<(int)(E / 256), 256, 0, stream>>>(efeats, src, dst, W_edge, w_coef,
                                                 p, q, feat, exbuf, deg);
    k_scan1<<<nb, 256, 0, stream>>>(deg, bsum, N);
    k_scan2<<<1, 64, 0, stream>>>(bsum, bpre, off, nb, N);
    k_scan3<<<nb, 256, 0, stream>>>(deg, bpre, off, N);
    k_scatter<<<(int)((E + 255) / 256), 256, 0, stream>>>(src, dst, exbuf, off,
                                                          cursor, pairs, E);
    k5_aggregate<<<(N + 3) / 4, 256, 0, stream>>>(off, pairs, z, h, N);
}

// Round 7
// 612.705 us; speedup vs baseline: 3.2857x; 1.0782x over previous
//
#include <hip/hip_runtime.h>
#include <hip/hip_bf16.h>

// GAT layer: N=50000 nodes, E=1.6M edges, DIN_N=128, DIN_E=64, DOUT_N=DOUT_E=64.
//   z = nfeats @ W_fc.T; p = W1@z + b; q = W3@z          (K12, fused; p/q stored bf16)
//   feat[e] = lrelu([ef | p[src] | q[dst]] @ [W2; I; I])  (K3, K=192 MFMA,
//                         identity-B frags do the A->C transpose of p/q)
//   a = lrelu(lrelu(feat . wc)); ex = exp(a); deg[dst]++  (K3)
//   off = exscan(deg)  (scan1/2/3, multi-block)
//   pairs[off[d]+cur] = {src, ex}                         (scatter)
//   h[n] = sum(ex * z[src]) / sum(ex)                     (K5, wave/node)
// Segment-max skipped: a is O(+-4) so exp cannot overflow; alpha identical.
// R6->R7: ef prefetched one tile ahead (was the residual ~900cy stall);
// p/q stored bf16 (no pack VALU, half buffer regs, half gather demand);
// launch_bounds ",2" removed (it cost occupancy 42->31%).

typedef __attribute__((ext_vector_type(8))) short short8;
typedef __attribute__((ext_vector_type(4))) float f32x4;
typedef __attribute__((ext_vector_type(2))) int i32x2;

__device__ __forceinline__ short bf1(float f) {
    union { __hip_bfloat16 h; short s; } u;
    u.h = __float2bfloat16(f);          // compiler emits v_cvt_pk_bf16_f32 pairs
    return u.s;
}

__device__ __forceinline__ short8 pack8(f32x4 a, f32x4 b) {
    short8 r;
    r[0] = bf1(a[0]); r[1] = bf1(a[1]); r[2] = bf1(a[2]); r[3] = bf1(a[3]);
    r[4] = bf1(b[0]); r[5] = bf1(b[1]); r[6] = bf1(b[2]); r[7] = bf1(b[3]);
    return r;
}

__device__ __forceinline__ f32x4 ntld4(const float* p) {
    return __builtin_nontemporal_load((const f32x4*)p);
}

__device__ __forceinline__ f32x4 ld4(const float* p) {
    return *(const f32x4*)p;
}

#define MFMA16(A, B, C) __builtin_amdgcn_mfma_f32_16x16x32_bf16((A), (B), (C), 0, 0, 0)

// ---------------- K12: z = nfeats@W_fc.T; p = W1@z+b; q = W3@z (bf16) --------
__global__ __launch_bounds__(256) void k12_node(
    const float* __restrict__ nfeats, const float* __restrict__ W_fc,
    const float* __restrict__ W_edge, const float* __restrict__ b_edge,
    float* __restrict__ z, unsigned short* __restrict__ p_bf,
    unsigned short* __restrict__ q_bf)
{
    __shared__ float WT[128 * 64];   // WT[k][c] = W_fc[c][k]
    __shared__ float W1T[64 * 64];   // W1T[k][c] = W_edge[c][k]
    __shared__ float W3T[64 * 64];   // W3T[k][c] = W_edge[c][128+k]
    __shared__ float zbuf[4][4][64];
    const int tid = threadIdx.x;
    for (int i = tid; i < 64 * 128; i += 256) {
        int c = i >> 7, k = i & 127;
        WT[k * 64 + c] = W_fc[i];
    }
    for (int i = tid; i < 64 * 64; i += 256) {
        int c = i >> 6, k = i & 63;
        W1T[k * 64 + c] = W_edge[c * 192 + k];
        W3T[k * 64 + c] = W_edge[c * 192 + 128 + k];
    }
    __syncthreads();
    const int wave = tid >> 6, lane = tid & 63;
    const float bias = b_edge[lane];
    const int nb = blockIdx.x * 16 + wave * 4;
    for (int j = 0; j < 4; ++j) {
        const int n = nb + j;
        const float* x = nfeats + (long)n * 128;
        float acc = 0.f;
#pragma unroll
        for (int k4 = 0; k4 < 32; ++k4) {
            f32x4 xv = ntld4(x + k4 * 4);
            acc += xv[0] * WT[(k4 * 4 + 0) * 64 + lane];
            acc += xv[1] * WT[(k4 * 4 + 1) * 64 + lane];
            acc += xv[2] * WT[(k4 * 4 + 2) * 64 + lane];
            acc += xv[3] * WT[(k4 * 4 + 3) * 64 + lane];
        }
        zbuf[wave][j][lane] = acc;
        z[(long)n * 64 + lane] = acc;
    }
    for (int j = 0; j < 4; ++j) {
        const int n = nb + j;
        float ap = bias, aq = 0.f;
#pragma unroll
        for (int k = 0; k < 64; ++k) {
            const float zk = zbuf[wave][j][k];
            ap += zk * W1T[k * 64 + lane];
            aq += zk * W3T[k * 64 + lane];
        }
        p_bf[(long)n * 64 + lane] = (unsigned short)bf1(ap);
        q_bf[(long)n * 64 + lane] = (unsigned short)bf1(aq);
    }
}

// ---------------- K3: per-edge K=192 MFMA + logits + deg (pipelined) ----------
// C/D layout (m89-verified): col = lane&15, row = (lane>>4)*4 + reg.
// A/B fragments filled with the same (g,j)->k bijection (validated R1/R2/R5).
// PQ[0..3] = {p k0..31, p k32..63, q k0..31, q k32..63} as bf16 short8.
#define LOAD_PQ(T, PQ) {                                                    \
    const int sE_ = __shfl(sAll, (T) * 16 + l15, 64);                       \
    const int dE_ = __shfl(dAll, (T) * 16 + l15, 64);                       \
    const unsigned short* pp_ = p_bf + (long)sE_ * 64 + g * 8;              \
    PQ[0] = *(const short8*)pp_;                                            \
    PQ[1] = *(const short8*)(pp_ + 32);                                     \
    const unsigned short* qp_ = q_bf + (long)dE_ * 64 + g * 8;              \
    PQ[2] = *(const short8*)qp_;                                            \
    PQ[3] = *(const short8*)(qp_ + 32);                                     \
}

#define LOAD_EF(T, EF) {                                                    \
    const float* efp_ = efeats + (wbase + (T) * 16 + l15) * 64 + g * 8;     \
    EF[0] = ntld4(efp_);      EF[1] = ntld4(efp_ + 4);                      \
    EF[2] = ntld4(efp_ + 32); EF[3] = ntld4(efp_ + 36);                     \
}

#define DO_TILE(T, PQ, EF, PREFETCH) {                                      \
    const long eb_ = wbase + (T) * 16;                                      \
    PREFETCH                                                                \
    f32x4 acc_[4];                                                          \
    _Pragma("unroll")                                                       \
    for (int t = 0; t < 4; ++t) acc_[t] = (f32x4){0.f, 0.f, 0.f, 0.f};      \
    acc_[0] = MFMA16(PQ[0], IdA, acc_[0]);                                  \
    acc_[1] = MFMA16(PQ[0], IdB, acc_[1]);                                  \
    acc_[2] = MFMA16(PQ[1], IdA, acc_[2]);                                  \
    acc_[3] = MFMA16(PQ[1], IdB, acc_[3]);                                  \
    acc_[0] = MFMA16(PQ[2], IdA, acc_[0]);                                  \
    acc_[1] = MFMA16(PQ[2], IdB, acc_[1]);                                  \
    acc_[2] = MFMA16(PQ[3], IdA, acc_[2]);                                  \
    acc_[3] = MFMA16(PQ[3], IdB, acc_[3]);                                  \
    short8 Aef0_ = pack8(EF[0], EF[1]), Aef1_ = pack8(EF[2], EF[3]);        \
    _Pragma("unroll")                                                       \
    for (int t = 0; t < 4; ++t) {                                           \
        acc_[t] = MFMA16(Aef0_, Bef[0][t], acc_[t]);                        \
        acc_[t] = MFMA16(Aef1_, Bef[1][t], acc_[t]);                        \
    }                                                                       \
    float myex_ = 0.f;                                                      \
    _Pragma("unroll")                                                       \
    for (int r = 0; r < 4; ++r) {                                           \
        float s_ = 0.f;                                                     \
        _Pragma("unroll")                                                   \
        for (int t = 0; t < 4; ++t) {                                       \
            float v_ = acc_[t][r];                                          \
            v_ = (v_ >= 0.f) ? v_ : 0.01f * v_;                             \
            __builtin_nontemporal_store(v_,                                 \
                feat_out + (eb_ + g * 4 + r) * 64 + t * 16 + l15);          \
            s_ += v_ * wc[t];                                               \
        }                                                                   \
        s_ += __shfl_xor(s_, 1, 16);                                        \
        s_ += __shfl_xor(s_, 2, 16);                                        \
        s_ += __shfl_xor(s_, 4, 16);                                        \
        s_ += __shfl_xor(s_, 8, 16);                                        \
        s_ = (s_ >= 0.f) ? s_ : 0.01f * s_;                                 \
        s_ = (s_ >= 0.f) ? s_ : 0.01f * s_;                                 \
        const float ex_ = __expf(s_);                                       \
        if (l15 == r) myex_ = ex_;                                          \
    }                                                                       \
    const int dmine_ = __shfl(dAll, (T) * 16 + g * 4 + (l15 & 3), 64);      \
    if (l15 < 4) {                                                          \
        exbuf[eb_ + g * 4 + l15] = myex_;                                   \
        atomicAdd(&deg[dmine_], 1);                                         \
    }                                                                       \
}

__global__ __launch_bounds__(256) void k3_edges(
    const float* __restrict__ efeats, const int* __restrict__ src,
    const int* __restrict__ dst, const float* __restrict__ W_edge,
    const float* __restrict__ w_coef, const unsigned short* __restrict__ p_bf,
    const unsigned short* __restrict__ q_bf, float* __restrict__ feat_out,
    float* __restrict__ exbuf, int* __restrict__ deg)
{
    const int lane = threadIdx.x & 63;
    const int wave = threadIdx.x >> 6;
    const int l15 = lane & 15, g = lane >> 4;
    const long wbase = ((long)blockIdx.x * 4 + wave) * 64;

    // issue tile-0 ef loads first (address needs only blockIdx)
    f32x4 efA[4], efB[4];
    LOAD_EF(0, efA);
    // then the index loads
    const int sAll = src[wbase + lane];
    const int dAll = dst[wbase + lane];

    // W2 B-fragments (overlap with ef/idx loads in flight)
    short8 Bef[2][4];
    float wc[4];
#pragma unroll
    for (int t = 0; t < 4; ++t) {
        const int col = t * 16 + l15;
        wc[t] = w_coef[col];
#pragma unroll
        for (int kt = 0; kt < 2; ++kt) {
            const float* wp = W_edge + col * 192 + 64 + kt * 32 + g * 8;
            Bef[kt][t] = pack8(ld4(wp), ld4(wp + 4));
        }
    }
    // identity B-fragments: one-hot at kc == col (mod 32 block)
    const short one = (short)0x3F80;   // bf16 1.0
    short8 IdA, IdB;
#pragma unroll
    for (int jj = 0; jj < 8; ++jj) {
        IdA[jj] = (l15 == g * 8 + jj) ? one : (short)0;        // cols 0..15 / 32..47
        IdB[jj] = (16 + l15 == g * 8 + jj) ? one : (short)0;   // cols 16..31 / 48..63
    }

    short8 pqA[4], pqB[4];
    LOAD_PQ(0, pqA);
    DO_TILE(0, pqA, efA, { LOAD_EF(1, efB); LOAD_PQ(1, pqB); });
    DO_TILE(1, pqB, efB, { LOAD_EF(2, efA); LOAD_PQ(2, pqA); });
    DO_TILE(2, pqA, efA, { LOAD_EF(3, efB); LOAD_PQ(3, pqB); });
    DO_TILE(3, pqB, efB, );
}

// ---------------- scan1: per-block (1024 elems) totals ----------------
__global__ __launch_bounds__(256) void k_scan1(
    const int* __restrict__ deg, int* __restrict__ bsum, int N)
{
    __shared__ int ws4[4];
    const int tid = threadIdx.x, lane = tid & 63, wave = tid >> 6;
    const int i0 = blockIdx.x * 1024 + tid * 4;
    int s = 0;
#pragma unroll
    for (int jj = 0; jj < 4; ++jj) {
        const int i = i0 + jj;
        if (i < N) s += deg[i];
    }
#pragma unroll
    for (int d = 1; d < 64; d <<= 1) s += __shfl_xor(s, d, 64);
    if (lane == 0) ws4[wave] = s;
    __syncthreads();
    if (tid == 0) bsum[blockIdx.x] = ws4[0] + ws4[1] + ws4[2] + ws4[3];
}

// ---------------- scan2: scan of block totals (<=64 blocks) ----------------
__global__ __launch_bounds__(64) void k_scan2(
    const int* __restrict__ bsum, int* __restrict__ bpre,
    int* __restrict__ off, int nb, int N)
{
    const int t = threadIdx.x;
    const int v = (t < nb) ? bsum[t] : 0;
    int x = v;
#pragma unroll
    for (int d = 1; d < 64; d <<= 1) {
        int y = __shfl_up(x, d, 64);
        if (t >= d) x += y;
    }
    if (t < nb) bpre[t] = x - v;
    if (t == 63) off[N] = x;   // grand total == E
}

// ---------------- scan3: write off[i] ----------------
__global__ __launch_bounds__(256) void k_scan3(
    const int* __restrict__ deg, const int* __restrict__ bpre,
    int* __restrict__ off, int N)
{
    __shared__ int ws4[4];
    const int tid = threadIdx.x, lane = tid & 63, wave = tid >> 6;
    const int i0 = blockIdx.x * 1024 + tid * 4;
    int v[4];
#pragma unroll
    for (int jj = 0; jj < 4; ++jj) {
        const int i = i0 + jj;
        v[jj] = (i < N) ? deg[i] : 0;
    }
    const int s = v[0] + v[1] + v[2] + v[3];
    int x = s;
#pragma unroll
    for (int d = 1; d < 64; d <<= 1) {
        int y = __shfl_up(x, d, 64);
        if (lane >= d) x += y;
    }
    if (lane == 63) ws4[wave] = x;
    __syncthreads();
    int wpre = 0;
#pragma unroll
    for (int w = 0; w < 4; ++w) if (w < wave) wpre += ws4[w];
    int run = bpre[blockIdx.x] + wpre + (x - s);
#pragma unroll
    for (int jj = 0; jj < 4; ++jj) {
        const int i = i0 + jj;
        if (i < N) off[i] = run;
        run += v[jj];
    }
}

// ---------------- scatter: pairs[pos] = {src, ex} sorted by dst ----------------
__global__ __launch_bounds__(256) void k_scatter(
    const int* __restrict__ src, const int* __restrict__ dst,
    const float* __restrict__ exbuf, const int* __restrict__ off,
    int* __restrict__ cursor, i32x2* __restrict__ pairs, long E)
{
    const long e = (long)blockIdx.x * 256 + threadIdx.x;
    if (e >= E) return;
    const int d = dst[e];
    const int pos = off[d] + atomicAdd(&cursor[d], 1);
    i32x2 pr;
    pr[0] = src[e];
    pr[1] = __float_as_int(exbuf[e]);
    pairs[pos] = pr;
}

// ---------------- K5: h[n] = sum(ex*z[src]) / sum(ex) ----------------
// one wave per node; lane = channel. Inner loop unrolled x4 with 4 accs;
// invalid lanes hold {0,0} so padded iterations add exactly 0.
__global__ __launch_bounds__(256) void k5_aggregate(
    const int* __restrict__ off, const i32x2* __restrict__ pairs,
    const float* __restrict__ z, float* __restrict__ h, int N)
{
    const int wave = threadIdx.x >> 6, lane = threadIdx.x & 63;
    const int n = blockIdx.x * 4 + wave;
    if (n >= N) return;
    const int beg = off[n], end = off[n + 1];
    float den = 0.f;
    float a0 = 0.f, a1 = 0.f, a2 = 0.f, a3 = 0.f;
    for (int base = beg; base < end; base += 64) {
        const int rem = end - base;
        i32x2 pr = (i32x2){0, 0};
        if (lane < rem) pr = __builtin_nontemporal_load(&pairs[base + lane]);
        const float ex = __int_as_float(pr[1]);
        float t = ex;
#pragma unroll
        for (int d = 1; d < 64; d <<= 1) t += __shfl_xor(t, d, 64);
        den += t;
        const int cnt = rem < 64 ? rem : 64;
        const int cnt4 = (cnt + 3) & ~3;
        for (int j = 0; j < cnt4; j += 4) {
            const int s0 = __shfl(pr[0], j, 64);
            const int s1 = __shfl(pr[0], j + 1, 64);
            const int s2 = __shfl(pr[0], j + 2, 64);
            const int s3 = __shfl(pr[0], j + 3, 64);
            const float e0 = __shfl(ex, j, 64);
            const float e1 = __shfl(ex, j + 1, 64);
            const float e2 = __shfl(ex, j + 2, 64);
            const float e3 = __shfl(ex, j + 3, 64);
            a0 = fmaf(e0, z[(long)s0 * 64 + lane], a0);
            a1 = fmaf(e1, z[(long)s1 * 64 + lane], a1);
            a2 = fmaf(e2, z[(long)s2 * 64 + lane], a2);
            a3 = fmaf(e3, z[(long)s3 * 64 + lane], a3);
        }
    }
    const float acc = (a0 + a1) + (a2 + a3);
    __builtin_nontemporal_store((end > beg) ? acc / den : 0.f,
                                h + (long)n * 64 + lane);
}

extern "C" void kernel_launch(void* const* d_in, const int* in_sizes, int n_in,
                              void* d_out, int out_size, void* d_ws, size_t ws_size,
                              hipStream_t stream) {
    const float* nfeats = (const float*)d_in[0];
    const float* efeats = (const float*)d_in[1];
    const int*   src    = (const int*)d_in[2];
    const int*   dst    = (const int*)d_in[3];
    const float* W_fc   = (const float*)d_in[4];
    const float* W_edge = (const float*)d_in[5];
    const float* b_edge = (const float*)d_in[6];
    const float* w_coef = (const float*)d_in[7];

    const int  N = in_sizes[0] / 128;   // 50000
    const long E = in_sizes[2];         // 1600000
    const int  nb = (N + 1023) / 1024;  // 49

    float* h    = (float*)d_out;                 // [N,64]
    float* feat = (float*)d_out + (long)N * 64;  // [E,64]

    float*          z      = (float*)d_ws;                 // N*64 f32
    unsigned short* p_bf   = (unsigned short*)(z + (long)N * 64);  // N*64 bf16
    unsigned short* q_bf   = p_bf + (long)N * 64;                  // N*64 bf16
    float*          exbuf  = (float*)(q_bf + (long)N * 64);        // E
    int*            deg    = (int*)(exbuf + E);            // N
    int*            cursor = deg + N;                      // N
    int*            off    = cursor + N;                   // N+2 (8B-align pairs)
    i32x2*          pairs  = (i32x2*)(off + N + 2);        // E
    int*            bsum   = (int*)(pairs + E);            // 64
    int*            bpre   = bsum + 64;                    // 64

    (void)hipMemsetAsync(deg, 0, (size_t)2 * N * sizeof(int), stream);  // deg+cursor

    k12_node<<<N / 16, 256, 0, stream>>>(nfeats, W_fc, W_edge, b_edge, z, p_bf, q_bf);
    k3_edges<<<(int)(E / 256), 256, 0, stream>>>(efeats, src, dst, W_edge, w_coef,
                                                 p_bf, q_bf, feat, exbuf, deg);
    k_scan1<<<nb, 256, 0, stream>>>(deg, bsum, N);
    k_scan2<<<1, 64, 0, stream>>>(bsum, bpre, off, nb, N);
    k_scan3<<<nb, 256, 0, stream>>>(deg, bpre, off, N);
    k_scatter<<<(int)((E + 255) / 256), 256, 0, stream>>>(src, dst, exbuf, off,
                                                          cursor, pairs, E);
    k5_aggregate<<<(N + 3) / 4, 256, 0, stream>>>(off, pairs, z, h, N);
}

// Round 8
// 516.384 us; speedup vs baseline: 3.8986x; 1.1865x over previous
//
#include <hip/hip_runtime.h>
#include <hip/hip_bf16.h>

// GAT layer: N=50000 nodes, E=1.6M edges, DIN_N=128, DIN_E=64, DOUT_N=DOUT_E=64.
//   Wp = W1@W_fc, Wq = W3@W_fc                           (k0, 64x128 each, bf16)
//   z = x@W_fc.T; p = x@Wp.T + b; q = x@Wq.T             (k12, one MFMA GEMM, bf16 out)
//   feat[e] = lrelu([ef | p[src] | q[dst]] @ [W2; I; I])  (K3, K=192 MFMA,
//                         identity-B frags do the A->C transpose of p/q)
//   a = lrelu(lrelu(feat . wc)); ex = exp(a); deg[dst]++  (K3)
//   off = exscan(deg)  (scan1/2/3); pairs[off[d]+cur] = {src, ex}  (scatter)
//   h[n] = sum(ex * z_bf[src]) / sum(ex)                  (K5, wave/node)
// Segment-max skipped: a is O(+-4) so exp cannot overflow; alpha identical.
// R7->R8: k3 W2-frags in LDS (conflict-free per-lane short8) + 8 tiles/wave +
// launch_bounds(256,8) for 8 waves/SIMD; z/p/q fully MFMA via Wp/Wq fold;
// z stored bf16 (halves k5 gather traffic).

typedef __attribute__((ext_vector_type(8))) short short8;
typedef __attribute__((ext_vector_type(4))) float f32x4;
typedef __attribute__((ext_vector_type(2))) int i32x2;

__device__ __forceinline__ short bf1(float f) {
    union { __hip_bfloat16 h; short s; } u;
    u.h = __float2bfloat16(f);          // compiler emits v_cvt_pk_bf16_f32 pairs
    return u.s;
}

__device__ __forceinline__ float bf2f(unsigned short u) {
    union { unsigned v; float f; } w; w.v = ((unsigned)u) << 16; return w.f;
}

__device__ __forceinline__ short8 pack8(f32x4 a, f32x4 b) {
    short8 r;
    r[0] = bf1(a[0]); r[1] = bf1(a[1]); r[2] = bf1(a[2]); r[3] = bf1(a[3]);
    r[4] = bf1(b[0]); r[5] = bf1(b[1]); r[6] = bf1(b[2]); r[7] = bf1(b[3]);
    return r;
}

__device__ __forceinline__ f32x4 ntld4(const float* p) {
    return __builtin_nontemporal_load((const f32x4*)p);
}

__device__ __forceinline__ f32x4 ld4(const float* p) {
    return *(const f32x4*)p;
}

#define MFMA16(A, B, C) __builtin_amdgcn_mfma_f32_16x16x32_bf16((A), (B), (C), 0, 0, 0)

// ---------------- k0: Wp = W1@W_fc, Wq = W3@W_fc (bf16 out) ----------------
__global__ __launch_bounds__(256) void k0_wpq(
    const float* __restrict__ W_edge, const float* __restrict__ W_fc,
    unsigned short* __restrict__ wp_bf, unsigned short* __restrict__ wq_bf)
{
    const int i = blockIdx.x * 256 + threadIdx.x;   // 0..8191
    if (i >= 64 * 128) return;
    const int c = i >> 7, k = i & 127;
    float sp = 0.f, sq = 0.f;
    for (int j = 0; j < 64; ++j) {
        const float f = W_fc[j * 128 + k];
        sp += W_edge[c * 192 + j] * f;
        sq += W_edge[c * 192 + 128 + j] * f;
    }
    wp_bf[i] = (unsigned short)bf1(sp);
    wq_bf[i] = (unsigned short)bf1(sq);
}

// ---------------- k12: z/p/q = x @ {W_fc,Wp,Wq}.T via MFMA ----------------
// C/D layout: col = lane&15, row = (lane>>4)*4 + reg (m89-verified).
__global__ __launch_bounds__(256) void k12_node(
    const float* __restrict__ nfeats, const float* __restrict__ W_fc,
    const unsigned short* __restrict__ wp_bf, const unsigned short* __restrict__ wq_bf,
    const float* __restrict__ b_edge,
    unsigned short* __restrict__ z_bf, unsigned short* __restrict__ p_bf,
    unsigned short* __restrict__ q_bf, int ntiles)
{
    const int lane = threadIdx.x & 63;
    const int wave = threadIdx.x >> 6;
    const int l15 = lane & 15, g = lane >> 4;
    const int ti = blockIdx.x * 4 + wave;
    if (ti >= ntiles) return;
    const int n0 = ti * 16;

    // A fragments: 16 nodes x K=128 of nfeats (bf16)
    const float* xp = nfeats + (long)(n0 + l15) * 128 + g * 8;
    short8 Ax[4];
#pragma unroll
    for (int kt = 0; kt < 4; ++kt)
        Ax[kt] = pack8(ntld4(xp + kt * 32), ntld4(xp + kt * 32 + 4));

#pragma unroll
    for (int t = 0; t < 4; ++t) {
        const int col = t * 16 + l15;
        f32x4 az = (f32x4){0.f, 0.f, 0.f, 0.f};
        f32x4 ap = az, aq = az;
#pragma unroll
        for (int kt = 0; kt < 4; ++kt) {
            const float* bz = W_fc + (long)col * 128 + kt * 32 + g * 8;
            az = MFMA16(Ax[kt], pack8(ld4(bz), ld4(bz + 4)), az);
            const short8 bp = *(const short8*)(wp_bf + (long)col * 128 + kt * 32 + g * 8);
            ap = MFMA16(Ax[kt], bp, ap);
            const short8 bq = *(const short8*)(wq_bf + (long)col * 128 + kt * 32 + g * 8);
            aq = MFMA16(Ax[kt], bq, aq);
        }
        const float bias = b_edge[col];
#pragma unroll
        for (int r = 0; r < 4; ++r) {
            const long row = n0 + g * 4 + r;
            z_bf[row * 64 + col] = (unsigned short)bf1(az[r]);
            p_bf[row * 64 + col] = (unsigned short)bf1(ap[r] + bias);
            q_bf[row * 64 + col] = (unsigned short)bf1(aq[r]);
        }
    }
}

// ---------------- K3: per-edge K=192 MFMA + logits + deg (pipelined) ----------
// C/D layout (m89-verified): col = lane&15, row = (lane>>4)*4 + reg.
// A/B fragments use the same (g,j)->k bijection (validated R1..R7).
// W2 fragments pre-packed in LDS per lane: W2f[s*64+lane], s = kt*4+t.
#define LOAD_PQ(T, PQ) {                                                    \
    const int sE_ = __shfl(((T) < 4) ? sAll0 : sAll1, ((T)&3) * 16 + l15, 64); \
    const int dE_ = __shfl(((T) < 4) ? dAll0 : dAll1, ((T)&3) * 16 + l15, 64); \
    const unsigned short* pp_ = p_bf + (long)sE_ * 64 + g * 8;              \
    PQ[0] = *(const short8*)pp_;                                            \
    PQ[1] = *(const short8*)(pp_ + 32);                                     \
    const unsigned short* qp_ = q_bf + (long)dE_ * 64 + g * 8;              \
    PQ[2] = *(const short8*)qp_;                                            \
    PQ[3] = *(const short8*)(qp_ + 32);                                     \
}

#define LOAD_EF(T, EF) {                                                    \
    const float* efp_ = efeats + (wbase + (T) * 16 + l15) * 64 + g * 8;     \
    EF[0] = ntld4(efp_);      EF[1] = ntld4(efp_ + 4);                      \
    EF[2] = ntld4(efp_ + 32); EF[3] = ntld4(efp_ + 36);                     \
}

#define DO_TILE(T, PQ, EF, PREFETCH) {                                      \
    const long eb_ = wbase + (T) * 16;                                      \
    PREFETCH                                                                \
    f32x4 acc_[4];                                                          \
    _Pragma("unroll")                                                       \
    for (int t = 0; t < 4; ++t) acc_[t] = (f32x4){0.f, 0.f, 0.f, 0.f};      \
    acc_[0] = MFMA16(PQ[0], IdA, acc_[0]);                                  \
    acc_[1] = MFMA16(PQ[0], IdB, acc_[1]);                                  \
    acc_[2] = MFMA16(PQ[1], IdA, acc_[2]);                                  \
    acc_[3] = MFMA16(PQ[1], IdB, acc_[3]);                                  \
    acc_[0] = MFMA16(PQ[2], IdA, acc_[0]);                                  \
    acc_[1] = MFMA16(PQ[2], IdB, acc_[1]);                                  \
    acc_[2] = MFMA16(PQ[3], IdA, acc_[2]);                                  \
    acc_[3] = MFMA16(PQ[3], IdB, acc_[3]);                                  \
    short8 Aef0_ = pack8(EF[0], EF[1]), Aef1_ = pack8(EF[2], EF[3]);        \
    _Pragma("unroll")                                                       \
    for (int t = 0; t < 4; ++t) {                                           \
        acc_[t] = MFMA16(Aef0_, W2f[t * 64 + lane], acc_[t]);               \
        acc_[t] = MFMA16(Aef1_, W2f[(4 + t) * 64 + lane], acc_[t]);         \
    }                                                                       \
    float myex_ = 0.f;                                                      \
    _Pragma("unroll")                                                       \
    for (int r = 0; r < 4; ++r) {                                           \
        float s_ = 0.f;                                                     \
        _Pragma("unroll")                                                   \
        for (int t = 0; t < 4; ++t) {                                       \
            float v_ = acc_[t][r];                                          \
            v_ = (v_ >= 0.f) ? v_ : 0.01f * v_;                             \
            __builtin_nontemporal_store(v_,                                 \
                feat_out + (eb_ + g * 4 + r) * 64 + t * 16 + l15);          \
            s_ += v_ * wc[t];                                               \
        }                                                                   \
        s_ += __shfl_xor(s_, 1, 16);                                        \
        s_ += __shfl_xor(s_, 2, 16);                                        \
        s_ += __shfl_xor(s_, 4, 16);                                        \
        s_ += __shfl_xor(s_, 8, 16);                                        \
        s_ = (s_ >= 0.f) ? s_ : 0.01f * s_;                                 \
        s_ = (s_ >= 0.f) ? s_ : 0.01f * s_;                                 \
        const float ex_ = __expf(s_);                                       \
        if (l15 == r) myex_ = ex_;                                          \
    }                                                                       \
    const int dmine_ = __shfl(((T) < 4) ? dAll0 : dAll1,                    \
                              ((T)&3) * 16 + g * 4 + (l15 & 3), 64);        \
    if (l15 < 4) {                                                          \
        exbuf[eb_ + g * 4 + l15] = myex_;                                   \
        atomicAdd(&deg[dmine_], 1);                                         \
    }                                                                       \
}

__global__ __launch_bounds__(256, 8) void k3_edges(
    const float* __restrict__ efeats, const int* __restrict__ src,
    const int* __restrict__ dst, const float* __restrict__ W_edge,
    const float* __restrict__ w_coef, const unsigned short* __restrict__ p_bf,
    const unsigned short* __restrict__ q_bf, float* __restrict__ feat_out,
    float* __restrict__ exbuf, int* __restrict__ deg)
{
    __shared__ short8 W2f[512];   // [s=kt*4+t][lane] pre-packed W2 B-frags, 8KB

    const int tid = threadIdx.x;
    const int lane = tid & 63;
    const int wave = tid >> 6;
    const int l15 = lane & 15, g = lane >> 4;
    const long wbase = ((long)blockIdx.x * 4 + wave) * 128;

    // issue tile-0 ef loads first (address needs only blockIdx)
    f32x4 efA[4], efB[4];
    LOAD_EF(0, efA);
    const int sAll0 = src[wbase + lane];
    const int dAll0 = dst[wbase + lane];
    const int sAll1 = src[wbase + 64 + lane];
    const int dAll1 = dst[wbase + 64 + lane];

    // fill W2 fragment LDS: frag fi -> (s = fi>>6, l = fi&63)
#pragma unroll
    for (int jj = 0; jj < 2; ++jj) {
        const int fi = tid + jj * 256;
        const int s = fi >> 6, l = fi & 63;
        const int col = (s & 3) * 16 + (l & 15);
        const int gg = l >> 4, kt = s >> 2;
        const float* wp = W_edge + col * 192 + 64 + kt * 32 + gg * 8;
        W2f[fi] = pack8(ld4(wp), ld4(wp + 4));
    }

    float wc[4];
#pragma unroll
    for (int t = 0; t < 4; ++t) wc[t] = w_coef[t * 16 + l15];

    // identity B-fragments: one-hot at kc == col (mod 32 block)
    const short one = (short)0x3F80;   // bf16 1.0
    short8 IdA, IdB;
#pragma unroll
    for (int jj = 0; jj < 8; ++jj) {
        IdA[jj] = (l15 == g * 8 + jj) ? one : (short)0;        // cols 0..15 / 32..47
        IdB[jj] = (16 + l15 == g * 8 + jj) ? one : (short)0;   // cols 16..31 / 48..63
    }
    __syncthreads();

    short8 pqA[4], pqB[4];
    LOAD_PQ(0, pqA);
    DO_TILE(0, pqA, efA, { LOAD_EF(1, efB); LOAD_PQ(1, pqB); });
    DO_TILE(1, pqB, efB, { LOAD_EF(2, efA); LOAD_PQ(2, pqA); });
    DO_TILE(2, pqA, efA, { LOAD_EF(3, efB); LOAD_PQ(3, pqB); });
    DO_TILE(3, pqB, efB, { LOAD_EF(4, efA); LOAD_PQ(4, pqA); });
    DO_TILE(4, pqA, efA, { LOAD_EF(5, efB); LOAD_PQ(5, pqB); });
    DO_TILE(5, pqB, efB, { LOAD_EF(6, efA); LOAD_PQ(6, pqA); });
    DO_TILE(6, pqA, efA, { LOAD_EF(7, efB); LOAD_PQ(7, pqB); });
    DO_TILE(7, pqB, efB, );
}

// ---------------- scan1: per-block (1024 elems) totals ----------------
__global__ __launch_bounds__(256) void k_scan1(
    const int* __restrict__ deg, int* __restrict__ bsum, int N)
{
    __shared__ int ws4[4];
    const int tid = threadIdx.x, lane = tid & 63, wave = tid >> 6;
    const int i0 = blockIdx.x * 1024 + tid * 4;
    int s = 0;
#pragma unroll
    for (int jj = 0; jj < 4; ++jj) {
        const int i = i0 + jj;
        if (i < N) s += deg[i];
    }
#pragma unroll
    for (int d = 1; d < 64; d <<= 1) s += __shfl_xor(s, d, 64);
    if (lane == 0) ws4[wave] = s;
    __syncthreads();
    if (tid == 0) bsum[blockIdx.x] = ws4[0] + ws4[1] + ws4[2] + ws4[3];
}

// ---------------- scan2: scan of block totals (<=64 blocks) ----------------
__global__ __launch_bounds__(64) void k_scan2(
    const int* __restrict__ bsum, int* __restrict__ bpre,
    int* __restrict__ off, int nb, int N)
{
    const int t = threadIdx.x;
    const int v = (t < nb) ? bsum[t] : 0;
    int x = v;
#pragma unroll
    for (int d = 1; d < 64; d <<= 1) {
        int y = __shfl_up(x, d, 64);
        if (t >= d) x += y;
    }
    if (t < nb) bpre[t] = x - v;
    if (t == 63) off[N] = x;   // grand total == E
}

// ---------------- scan3: write off[i] ----------------
__global__ __launch_bounds__(256) void k_scan3(
    const int* __restrict__ deg, const int* __restrict__ bpre,
    int* __restrict__ off, int N)
{
    __shared__ int ws4[4];
    const int tid = threadIdx.x, lane = tid & 63, wave = tid >> 6;
    const int i0 = blockIdx.x * 1024 + tid * 4;
    int v[4];
#pragma unroll
    for (int jj = 0; jj < 4; ++jj) {
        const int i = i0 + jj;
        v[jj] = (i < N) ? deg[i] : 0;
    }
    const int s = v[0] + v[1] + v[2] + v[3];
    int x = s;
#pragma unroll
    for (int d = 1; d < 64; d <<= 1) {
        int y = __shfl_up(x, d, 64);
        if (lane >= d) x += y;
    }
    if (lane == 63) ws4[wave] = x;
    __syncthreads();
    int wpre = 0;
#pragma unroll
    for (int w = 0; w < 4; ++w) if (w < wave) wpre += ws4[w];
    int run = bpre[blockIdx.x] + wpre + (x - s);
#pragma unroll
    for (int jj = 0; jj < 4; ++jj) {
        const int i = i0 + jj;
        if (i < N) off[i] = run;
        run += v[jj];
    }
}

// ---------------- scatter: pairs[pos] = {src, ex} sorted by dst ----------------
__global__ __launch_bounds__(256) void k_scatter(
    const int* __restrict__ src, const int* __restrict__ dst,
    const float* __restrict__ exbuf, const int* __restrict__ off,
    int* __restrict__ cursor, i32x2* __restrict__ pairs, long E)
{
    const long e = (long)blockIdx.x * 256 + threadIdx.x;
    if (e >= E) return;
    const int d = dst[e];
    const int pos = off[d] + atomicAdd(&cursor[d], 1);
    i32x2 pr;
    pr[0] = src[e];
    pr[1] = __float_as_int(exbuf[e]);
    pairs[pos] = pr;
}

// ---------------- K5: h[n] = sum(ex*z[src]) / sum(ex) ----------------
// one wave per node; lane = channel; z gathered as bf16 (128B rows).
__global__ __launch_bounds__(256) void k5_aggregate(
    const int* __restrict__ off, const i32x2* __restrict__ pairs,
    const unsigned short* __restrict__ z_bf, float* __restrict__ h, int N)
{
    const int wave = threadIdx.x >> 6, lane = threadIdx.x & 63;
    const int n = blockIdx.x * 4 + wave;
    if (n >= N) return;
    const int beg = off[n], end = off[n + 1];
    float den = 0.f;
    float a0 = 0.f, a1 = 0.f, a2 = 0.f, a3 = 0.f;
    for (int base = beg; base < end; base += 64) {
        const int rem = end - base;
        i32x2 pr = (i32x2){0, 0};
        if (lane < rem) pr = __builtin_nontemporal_load(&pairs[base + lane]);
        const float ex = __int_as_float(pr[1]);
        float t = ex;
#pragma unroll
        for (int d = 1; d < 64; d <<= 1) t += __shfl_xor(t, d, 64);
        den += t;
        const int cnt = rem < 64 ? rem : 64;
        const int cnt4 = (cnt + 3) & ~3;
        for (int j = 0; j < cnt4; j += 4) {
            const int s0 = __shfl(pr[0], j, 64);
            const int s1 = __shfl(pr[0], j + 1, 64);
            const int s2 = __shfl(pr[0], j + 2, 64);
            const int s3 = __shfl(pr[0], j + 3, 64);
            const float e0 = __shfl(ex, j, 64);
            const float e1 = __shfl(ex, j + 1, 64);
            const float e2 = __shfl(ex, j + 2, 64);
            const float e3 = __shfl(ex, j + 3, 64);
            a0 = fmaf(e0, bf2f(z_bf[(long)s0 * 64 + lane]), a0);
            a1 = fmaf(e1, bf2f(z_bf[(long)s1 * 64 + lane]), a1);
            a2 = fmaf(e2, bf2f(z_bf[(long)s2 * 64 + lane]), a2);
            a3 = fmaf(e3, bf2f(z_bf[(long)s3 * 64 + lane]), a3);
        }
    }
    const float acc = (a0 + a1) + (a2 + a3);
    __builtin_nontemporal_store((end > beg) ? acc / den : 0.f,
                                h + (long)n * 64 + lane);
}

extern "C" void kernel_launch(void* const* d_in, const int* in_sizes, int n_in,
                              void* d_out, int out_size, void* d_ws, size_t ws_size,
                              hipStream_t stream) {
    const float* nfeats = (const float*)d_in[0];
    const float* efeats = (const float*)d_in[1];
    const int*   src    = (const int*)d_in[2];
    const int*   dst    = (const int*)d_in[3];
    const float* W_fc   = (const float*)d_in[4];
    const float* W_edge = (const float*)d_in[5];
    const float* b_edge = (const float*)d_in[6];
    const float* w_coef = (const float*)d_in[7];

    const int  N = in_sizes[0] / 128;   // 50000
    const long E = in_sizes[2];         // 1600000
    const int  nb = (N + 1023) / 1024;  // 49
    const int  ntiles = N / 16;         // 3125

    float* h    = (float*)d_out;                 // [N,64]
    float* feat = (float*)d_out + (long)N * 64;  // [E,64]

    unsigned short* z_bf   = (unsigned short*)d_ws;        // N*64 bf16
    unsigned short* p_bf   = z_bf + (long)N * 64;          // N*64 bf16
    unsigned short* q_bf   = p_bf + (long)N * 64;          // N*64 bf16
    unsigned short* wp_bf  = q_bf + (long)N * 64;          // 64*128
    unsigned short* wq_bf  = wp_bf + 64 * 128;             // 64*128
    float*          exbuf  = (float*)(wq_bf + 64 * 128);   // E
    int*            deg    = (int*)(exbuf + E);            // N
    int*            cursor = deg + N;                      // N
    int*            off    = cursor + N;                   // N+2 (8B-align pairs)
    i32x2*          pairs  = (i32x2*)(off + N + 2);        // E
    int*            bsum   = (int*)(pairs + E);            // 64
    int*            bpre   = bsum + 64;                    // 64

    (void)hipMemsetAsync(deg, 0, (size_t)2 * N * sizeof(int), stream);  // deg+cursor

    k0_wpq<<<32, 256, 0, stream>>>(W_edge, W_fc, wp_bf, wq_bf);
    k12_node<<<(ntiles + 3) / 4, 256, 0, stream>>>(nfeats, W_fc, wp_bf, wq_bf,
                                                   b_edge, z_bf, p_bf, q_bf, ntiles);
    k3_edges<<<(int)(E / 512), 256, 0, stream>>>(efeats, src, dst, W_edge, w_coef,
                                                 p_bf, q_bf, feat, exbuf, deg);
    k_scan1<<<nb, 256, 0, stream>>>(deg, bsum, N);
    k_scan2<<<1, 64, 0, stream>>>(bsum, bpre, off, nb, N);
    k_scan3<<<nb, 256, 0, stream>>>(deg, bpre, off, N);
    k_scatter<<<(int)((E + 255) / 256), 256, 0, stream>>>(src, dst, exbuf, off,
                                                          cursor, pairs, E);
    k5_aggregate<<<(N + 3) / 4, 256, 0, stream>>>(off, pairs, z_bf, h, N);
}

// Round 9
// 425.692 us; speedup vs baseline: 4.7292x; 1.2130x over previous
//
#include <hip/hip_runtime.h>
#include <hip/hip_bf16.h>

// GAT layer: N=50000 nodes, E=1.6M edges, DIN_N=128, DIN_E=64, DOUT_N=DOUT_E=64.
//   Wp = W1@W_fc, Wq = W3@W_fc                           (k0, 64x128 each, bf16)
//   z = x@W_fc.T; p = x@Wp.T + b; q = x@Wq.T             (k12, one MFMA GEMM, bf16 out)
//   feat[e] = lrelu([ef | p[src] | q[dst]] @ [W2; I; I])  (K3, K=192 MFMA,
//                         identity-B frags do the A->C transpose of p/q)
//   a = lrelu(lrelu(feat . wc)); ex = exp(a); deg[dst]++  (K3)
//   off = exscan(deg)  (scan1/2/3); pairs[off[d]+cur] = {src, ex}  (scatter)
//   h[n] = sum(ex * z_bf[src]) / sum(ex)                  (K5, wave/node)
// Segment-max skipped: a is O(+-4) so exp cannot overflow; alpha identical.
// R8->R9: launch_bounds(256,8) forced VGPR=32 -> pipeline spilled to scratch
// (+400MB HBM round-trip, k3 262->345us). Relax to (256,5): ~102 VGPR cap
// keeps ef/pq double-buffers in registers at 5 waves/SIMD.

typedef __attribute__((ext_vector_type(8))) short short8;
typedef __attribute__((ext_vector_type(4))) float f32x4;
typedef __attribute__((ext_vector_type(2))) int i32x2;

__device__ __forceinline__ short bf1(float f) {
    union { __hip_bfloat16 h; short s; } u;
    u.h = __float2bfloat16(f);          // compiler emits v_cvt_pk_bf16_f32 pairs
    return u.s;
}

__device__ __forceinline__ float bf2f(unsigned short u) {
    union { unsigned v; float f; } w; w.v = ((unsigned)u) << 16; return w.f;
}

__device__ __forceinline__ short8 pack8(f32x4 a, f32x4 b) {
    short8 r;
    r[0] = bf1(a[0]); r[1] = bf1(a[1]); r[2] = bf1(a[2]); r[3] = bf1(a[3]);
    r[4] = bf1(b[0]); r[5] = bf1(b[1]); r[6] = bf1(b[2]); r[7] = bf1(b[3]);
    return r;
}

__device__ __forceinline__ f32x4 ntld4(const float* p) {
    return __builtin_nontemporal_load((const f32x4*)p);
}

__device__ __forceinline__ f32x4 ld4(const float* p) {
    return *(const f32x4*)p;
}

#define MFMA16(A, B, C) __builtin_amdgcn_mfma_f32_16x16x32_bf16((A), (B), (C), 0, 0, 0)

// ---------------- k0: Wp = W1@W_fc, Wq = W3@W_fc (bf16 out) ----------------
__global__ __launch_bounds__(256) void k0_wpq(
    const float* __restrict__ W_edge, const float* __restrict__ W_fc,
    unsigned short* __restrict__ wp_bf, unsigned short* __restrict__ wq_bf)
{
    const int i = blockIdx.x * 256 + threadIdx.x;   // 0..8191
    if (i >= 64 * 128) return;
    const int c = i >> 7, k = i & 127;
    float sp = 0.f, sq = 0.f;
    for (int j = 0; j < 64; ++j) {
        const float f = W_fc[j * 128 + k];
        sp += W_edge[c * 192 + j] * f;
        sq += W_edge[c * 192 + 128 + j] * f;
    }
    wp_bf[i] = (unsigned short)bf1(sp);
    wq_bf[i] = (unsigned short)bf1(sq);
}

// ---------------- k12: z/p/q = x @ {W_fc,Wp,Wq}.T via MFMA ----------------
// C/D layout: col = lane&15, row = (lane>>4)*4 + reg (m89-verified).
__global__ __launch_bounds__(256) void k12_node(
    const float* __restrict__ nfeats, const float* __restrict__ W_fc,
    const unsigned short* __restrict__ wp_bf, const unsigned short* __restrict__ wq_bf,
    const float* __restrict__ b_edge,
    unsigned short* __restrict__ z_bf, unsigned short* __restrict__ p_bf,
    unsigned short* __restrict__ q_bf, int ntiles)
{
    const int lane = threadIdx.x & 63;
    const int wave = threadIdx.x >> 6;
    const int l15 = lane & 15, g = lane >> 4;
    const int ti = blockIdx.x * 4 + wave;
    if (ti >= ntiles) return;
    const int n0 = ti * 16;

    // A fragments: 16 nodes x K=128 of nfeats (bf16)
    const float* xp = nfeats + (long)(n0 + l15) * 128 + g * 8;
    short8 Ax[4];
#pragma unroll
    for (int kt = 0; kt < 4; ++kt)
        Ax[kt] = pack8(ntld4(xp + kt * 32), ntld4(xp + kt * 32 + 4));

#pragma unroll
    for (int t = 0; t < 4; ++t) {
        const int col = t * 16 + l15;
        f32x4 az = (f32x4){0.f, 0.f, 0.f, 0.f};
        f32x4 ap = az, aq = az;
#pragma unroll
        for (int kt = 0; kt < 4; ++kt) {
            const float* bz = W_fc + (long)col * 128 + kt * 32 + g * 8;
            az = MFMA16(Ax[kt], pack8(ld4(bz), ld4(bz + 4)), az);
            const short8 bp = *(const short8*)(wp_bf + (long)col * 128 + kt * 32 + g * 8);
            ap = MFMA16(Ax[kt], bp, ap);
            const short8 bq = *(const short8*)(wq_bf + (long)col * 128 + kt * 32 + g * 8);
            aq = MFMA16(Ax[kt], bq, aq);
        }
        const float bias = b_edge[col];
#pragma unroll
        for (int r = 0; r < 4; ++r) {
            const long row = n0 + g * 4 + r;
            z_bf[row * 64 + col] = (unsigned short)bf1(az[r]);
            p_bf[row * 64 + col] = (unsigned short)bf1(ap[r] + bias);
            q_bf[row * 64 + col] = (unsigned short)bf1(aq[r]);
        }
    }
}

// ---------------- K3: per-edge K=192 MFMA + logits + deg (pipelined) ----------
// C/D layout (m89-verified): col = lane&15, row = (lane>>4)*4 + reg.
// A/B fragments use the same (g,j)->k bijection (validated R1..R7).
// W2 fragments pre-packed in LDS per lane: W2f[s*64+lane], s = kt*4+t.
#define LOAD_PQ(T, PQ) {                                                    \
    const int sE_ = __shfl(((T) < 4) ? sAll0 : sAll1, ((T)&3) * 16 + l15, 64); \
    const int dE_ = __shfl(((T) < 4) ? dAll0 : dAll1, ((T)&3) * 16 + l15, 64); \
    const unsigned short* pp_ = p_bf + (long)sE_ * 64 + g * 8;              \
    PQ[0] = *(const short8*)pp_;                                            \
    PQ[1] = *(const short8*)(pp_ + 32);                                     \
    const unsigned short* qp_ = q_bf + (long)dE_ * 64 + g * 8;              \
    PQ[2] = *(const short8*)qp_;                                            \
    PQ[3] = *(const short8*)(qp_ + 32);                                     \
}

#define LOAD_EF(T, EF) {                                                    \
    const float* efp_ = efeats + (wbase + (T) * 16 + l15) * 64 + g * 8;     \
    EF[0] = ntld4(efp_);      EF[1] = ntld4(efp_ + 4);                      \
    EF[2] = ntld4(efp_ + 32); EF[3] = ntld4(efp_ + 36);                     \
}

#define DO_TILE(T, PQ, EF, PREFETCH) {                                      \
    const long eb_ = wbase + (T) * 16;                                      \
    PREFETCH                                                                \
    f32x4 acc_[4];                                                          \
    _Pragma("unroll")                                                       \
    for (int t = 0; t < 4; ++t) acc_[t] = (f32x4){0.f, 0.f, 0.f, 0.f};      \
    acc_[0] = MFMA16(PQ[0], IdA, acc_[0]);                                  \
    acc_[1] = MFMA16(PQ[0], IdB, acc_[1]);                                  \
    acc_[2] = MFMA16(PQ[1], IdA, acc_[2]);                                  \
    acc_[3] = MFMA16(PQ[1], IdB, acc_[3]);                                  \
    acc_[0] = MFMA16(PQ[2], IdA, acc_[0]);                                  \
    acc_[1] = MFMA16(PQ[2], IdB, acc_[1]);                                  \
    acc_[2] = MFMA16(PQ[3], IdA, acc_[2]);                                  \
    acc_[3] = MFMA16(PQ[3], IdB, acc_[3]);                                  \
    short8 Aef0_ = pack8(EF[0], EF[1]), Aef1_ = pack8(EF[2], EF[3]);        \
    _Pragma("unroll")                                                       \
    for (int t = 0; t < 4; ++t) {                                           \
        acc_[t] = MFMA16(Aef0_, W2f[t * 64 + lane], acc_[t]);               \
        acc_[t] = MFMA16(Aef1_, W2f[(4 + t) * 64 + lane], acc_[t]);         \
    }                                                                       \
    float myex_ = 0.f;                                                      \
    _Pragma("unroll")                                                       \
    for (int r = 0; r < 4; ++r) {                                           \
        float s_ = 0.f;                                                     \
        _Pragma("unroll")                                                   \
        for (int t = 0; t < 4; ++t) {                                       \
            float v_ = acc_[t][r];                                          \
            v_ = (v_ >= 0.f) ? v_ : 0.01f * v_;                             \
            __builtin_nontemporal_store(v_,                                 \
                feat_out + (eb_ + g * 4 + r) * 64 + t * 16 + l15);          \
            s_ += v_ * wc[t];                                               \
        }                                                                   \
        s_ += __shfl_xor(s_, 1, 16);                                        \
        s_ += __shfl_xor(s_, 2, 16);                                        \
        s_ += __shfl_xor(s_, 4, 16);                                        \
        s_ += __shfl_xor(s_, 8, 16);                                        \
        s_ = (s_ >= 0.f) ? s_ : 0.01f * s_;                                 \
        s_ = (s_ >= 0.f) ? s_ : 0.01f * s_;                                 \
        const float ex_ = __expf(s_);                                       \
        if (l15 == r) myex_ = ex_;                                          \
    }                                                                       \
    const int dmine_ = __shfl(((T) < 4) ? dAll0 : dAll1,                    \
                              ((T)&3) * 16 + g * 4 + (l15 & 3), 64);        \
    if (l15 < 4) {                                                          \
        exbuf[eb_ + g * 4 + l15] = myex_;                                   \
        atomicAdd(&deg[dmine_], 1);                                         \
    }                                                                       \
}

__global__ __launch_bounds__(256, 5) void k3_edges(
    const float* __restrict__ efeats, const int* __restrict__ src,
    const int* __restrict__ dst, const float* __restrict__ W_edge,
    const float* __restrict__ w_coef, const unsigned short* __restrict__ p_bf,
    const unsigned short* __restrict__ q_bf, float* __restrict__ feat_out,
    float* __restrict__ exbuf, int* __restrict__ deg)
{
    __shared__ short8 W2f[512];   // [s=kt*4+t][lane] pre-packed W2 B-frags, 8KB

    const int tid = threadIdx.x;
    const int lane = tid & 63;
    const int wave = tid >> 6;
    const int l15 = lane & 15, g = lane >> 4;
    const long wbase = ((long)blockIdx.x * 4 + wave) * 128;

    // issue tile-0 ef loads first (address needs only blockIdx)
    f32x4 efA[4], efB[4];
    LOAD_EF(0, efA);
    const int sAll0 = src[wbase + lane];
    const int dAll0 = dst[wbase + lane];
    const int sAll1 = src[wbase + 64 + lane];
    const int dAll1 = dst[wbase + 64 + lane];

    // fill W2 fragment LDS: frag fi -> (s = fi>>6, l = fi&63)
#pragma unroll
    for (int jj = 0; jj < 2; ++jj) {
        const int fi = tid + jj * 256;
        const int s = fi >> 6, l = fi & 63;
        const int col = (s & 3) * 16 + (l & 15);
        const int gg = l >> 4, kt = s >> 2;
        const float* wp = W_edge + col * 192 + 64 + kt * 32 + gg * 8;
        W2f[fi] = pack8(ld4(wp), ld4(wp + 4));
    }

    float wc[4];
#pragma unroll
    for (int t = 0; t < 4; ++t) wc[t] = w_coef[t * 16 + l15];

    // identity B-fragments: one-hot at kc == col (mod 32 block)
    const short one = (short)0x3F80;   // bf16 1.0
    short8 IdA, IdB;
#pragma unroll
    for (int jj = 0; jj < 8; ++jj) {
        IdA[jj] = (l15 == g * 8 + jj) ? one : (short)0;        // cols 0..15 / 32..47
        IdB[jj] = (16 + l15 == g * 8 + jj) ? one : (short)0;   // cols 16..31 / 48..63
    }
    __syncthreads();

    short8 pqA[4], pqB[4];
    LOAD_PQ(0, pqA);
    DO_TILE(0, pqA, efA, { LOAD_EF(1, efB); LOAD_PQ(1, pqB); });
    DO_TILE(1, pqB, efB, { LOAD_EF(2, efA); LOAD_PQ(2, pqA); });
    DO_TILE(2, pqA, efA, { LOAD_EF(3, efB); LOAD_PQ(3, pqB); });
    DO_TILE(3, pqB, efB, { LOAD_EF(4, efA); LOAD_PQ(4, pqA); });
    DO_TILE(4, pqA, efA, { LOAD_EF(5, efB); LOAD_PQ(5, pqB); });
    DO_TILE(5, pqB, efB, { LOAD_EF(6, efA); LOAD_PQ(6, pqA); });
    DO_TILE(6, pqA, efA, { LOAD_EF(7, efB); LOAD_PQ(7, pqB); });
    DO_TILE(7, pqB, efB, );
}

// ---------------- scan1: per-block (1024 elems) totals ----------------
__global__ __launch_bounds__(256) void k_scan1(
    const int* __restrict__ deg, int* __restrict__ bsum, int N)
{
    __shared__ int ws4[4];
    const int tid = threadIdx.x, lane = tid & 63, wave = tid >> 6;
    const int i0 = blockIdx.x * 1024 + tid * 4;
    int s = 0;
#pragma unroll
    for (int jj = 0; jj < 4; ++jj) {
        const int i = i0 + jj;
        if (i < N) s += deg[i];
    }
#pragma unroll
    for (int d = 1; d < 64; d <<= 1) s += __shfl_xor(s, d, 64);
    if (lane == 0) ws4[wave] = s;
    __syncthreads();
    if (tid == 0) bsum[blockIdx.x] = ws4[0] + ws4[1] + ws4[2] + ws4[3];
}

// ---------------- scan2: scan of block totals (<=64 blocks) ----------------
__global__ __launch_bounds__(64) void k_scan2(
    const int* __restrict__ bsum, int* __restrict__ bpre,
    int* __restrict__ off, int nb, int N)
{
    const int t = threadIdx.x;
    const int v = (t < nb) ? bsum[t] : 0;
    int x = v;
#pragma unroll
    for (int d = 1; d < 64; d <<= 1) {
        int y = __shfl_up(x, d, 64);
        if (t >= d) x += y;
    }
    if (t < nb) bpre[t] = x - v;
    if (t == 63) off[N] = x;   // grand total == E
}

// ---------------- scan3: write off[i] ----------------
__global__ __launch_bounds__(256) void k_scan3(
    const int* __restrict__ deg, const int* __restrict__ bpre,
    int* __restrict__ off, int N)
{
    __shared__ int ws4[4];
    const int tid = threadIdx.x, lane = tid & 63, wave = tid >> 6;
    const int i0 = blockIdx.x * 1024 + tid * 4;
    int v[4];
#pragma unroll
    for (int jj = 0; jj < 4; ++jj) {
        const int i = i0 + jj;
        v[jj] = (i < N) ? deg[i] : 0;
    }
    const int s = v[0] + v[1] + v[2] + v[3];
    int x = s;
#pragma unroll
    for (int d = 1; d < 64; d <<= 1) {
        int y = __shfl_up(x, d, 64);
        if (lane >= d) x += y;
    }
    if (lane == 63) ws4[wave] = x;
    __syncthreads();
    int wpre = 0;
#pragma unroll
    for (int w = 0; w < 4; ++w) if (w < wave) wpre += ws4[w];
    int run = bpre[blockIdx.x] + wpre + (x - s);
#pragma unroll
    for (int jj = 0; jj < 4; ++jj) {
        const int i = i0 + jj;
        if (i < N) off[i] = run;
        run += v[jj];
    }
}

// ---------------- scatter: pairs[pos] = {src, ex} sorted by dst ----------------
__global__ __launch_bounds__(256) void k_scatter(
    const int* __restrict__ src, const int* __restrict__ dst,
    const float* __restrict__ exbuf, const int* __restrict__ off,
    int* __restrict__ cursor, i32x2* __restrict__ pairs, long E)
{
    const long e = (long)blockIdx.x * 256 + threadIdx.x;
    if (e >= E) return;
    const int d = dst[e];
    const int pos = off[d] + atomicAdd(&cursor[d], 1);
    i32x2 pr;
    pr[0] = src[e];
    pr[1] = __float_as_int(exbuf[e]);
    pairs[pos] = pr;
}

// ---------------- K5: h[n] = sum(ex*z[src]) / sum(ex) ----------------
// one wave per node; lane = channel; z gathered as bf16 (128B rows).
__global__ __launch_bounds__(256) void k5_aggregate(
    const int* __restrict__ off, const i32x2* __restrict__ pairs,
    const unsigned short* __restrict__ z_bf, float* __restrict__ h, int N)
{
    const int wave = threadIdx.x >> 6, lane = threadIdx.x & 63;
    const int n = blockIdx.x * 4 + wave;
    if (n >= N) return;
    const int beg = off[n], end = off[n + 1];
    float den = 0.f;
    float a0 = 0.f, a1 = 0.f, a2 = 0.f, a3 = 0.f;
    for (int base = beg; base < end; base += 64) {
        const int rem = end - base;
        i32x2 pr = (i32x2){0, 0};
        if (lane < rem) pr = __builtin_nontemporal_load(&pairs[base + lane]);
        const float ex = __int_as_float(pr[1]);
        float t = ex;
#pragma unroll
        for (int d = 1; d < 64; d <<= 1) t += __shfl_xor(t, d, 64);
        den += t;
        const int cnt = rem < 64 ? rem : 64;
        const int cnt4 = (cnt + 3) & ~3;
        for (int j = 0; j < cnt4; j += 4) {
            const int s0 = __shfl(pr[0], j, 64);
            const int s1 = __shfl(pr[0], j + 1, 64);
            const int s2 = __shfl(pr[0], j + 2, 64);
            const int s3 = __shfl(pr[0], j + 3, 64);
            const float e0 = __shfl(ex, j, 64);
            const float e1 = __shfl(ex, j + 1, 64);
            const float e2 = __shfl(ex, j + 2, 64);
            const float e3 = __shfl(ex, j + 3, 64);
            a0 = fmaf(e0, bf2f(z_bf[(long)s0 * 64 + lane]), a0);
            a1 = fmaf(e1, bf2f(z_bf[(long)s1 * 64 + lane]), a1);
            a2 = fmaf(e2, bf2f(z_bf[(long)s2 * 64 + lane]), a2);
            a3 = fmaf(e3, bf2f(z_bf[(long)s3 * 64 + lane]), a3);
        }
    }
    const float acc = (a0 + a1) + (a2 + a3);
    __builtin_nontemporal_store((end > beg) ? acc / den : 0.f,
                                h + (long)n * 64 + lane);
}

extern "C" void kernel_launch(void* const* d_in, const int* in_sizes, int n_in,
                              void* d_out, int out_size, void* d_ws, size_t ws_size,
                              hipStream_t stream) {
    const float* nfeats = (const float*)d_in[0];
    const float* efeats = (const float*)d_in[1];
    const int*   src    = (const int*)d_in[2];
    const int*   dst    = (const int*)d_in[3];
    const float* W_fc   = (const float*)d_in[4];
    const float* W_edge = (const float*)d_in[5];
    const float* b_edge = (const float*)d_in[6];
    const float* w_coef = (const float*)d_in[7];

    const int  N = in_sizes[0] / 128;   // 50000
    const long E = in_sizes[2];         // 1600000
    const int  nb = (N + 1023) / 1024;  // 49
    const int  ntiles = N / 16;         // 3125

    float* h    = (float*)d_out;                 // [N,64]
    float* feat = (float*)d_out + (long)N * 64;  // [E,64]

    unsigned short* z_bf   = (unsigned short*)d_ws;        // N*64 bf16
    unsigned short* p_bf   = z_bf + (long)N * 64;          // N*64 bf16
    unsigned short* q_bf   = p_bf + (long)N * 64;          // N*64 bf16
    unsigned short* wp_bf  = q_bf + (long)N * 64;          // 64*128
    unsigned short* wq_bf  = wp_bf + 64 * 128;             // 64*128
    float*          exbuf  = (float*)(wq_bf + 64 * 128);   // E
    int*            deg    = (int*)(exbuf + E);            // N
    int*            cursor = deg + N;                      // N
    int*            off    = cursor + N;                   // N+2 (8B-align pairs)
    i32x2*          pairs  = (i32x2*)(off + N + 2);        // E
    int*            bsum   = (int*)(pairs + E);            // 64
    int*            bpre   = bsum + 64;                    // 64

    (void)hipMemsetAsync(deg, 0, (size_t)2 * N * sizeof(int), stream);  // deg+cursor

    k0_wpq<<<32, 256, 0, stream>>>(W_edge, W_fc, wp_bf, wq_bf);
    k12_node<<<(ntiles + 3) / 4, 256, 0, stream>>>(nfeats, W_fc, wp_bf, wq_bf,
                                                   b_edge, z_bf, p_bf, q_bf, ntiles);
    k3_edges<<<(int)(E / 512), 256, 0, stream>>>(efeats, src, dst, W_edge, w_coef,
                                                 p_bf, q_bf, feat, exbuf, deg);
    k_scan1<<<nb, 256, 0, stream>>>(deg, bsum, N);
    k_scan2<<<1, 64, 0, stream>>>(bsum, bpre, off, nb, N);
    k_scan3<<<nb, 256, 0, stream>>>(deg, bpre, off, N);
    k_scatter<<<(int)((E + 255) / 256), 256, 0, stream>>>(src, dst, exbuf, off,
                                                          cursor, pairs, E);
    k5_aggregate<<<(N + 3) / 4, 256, 0, stream>>>(off, pairs, z_bf, h, N);
}